// Round 1
// baseline (241.893 us; speedup 1.0000x reference)
//
#include <hip/hip_runtime.h>
#include <math.h>

#define NB 16384
#define LH 50
#define D  64

typedef _Float16 half2v __attribute__((ext_vector_type(2)));
typedef _Float16 half8  __attribute__((ext_vector_type(8)));
typedef float    f32x16 __attribute__((ext_vector_type(16)));
typedef unsigned int u32;

#define MFMA(a, b, c) __builtin_amdgcn_mfma_f32_32x32x16_f16((a), (b), (c), 0, 0, 0)

// ---- fragment facts (32x32x16, verified m74/m101 + R3..R5 pass) ----
// A[m][k]: m=lane&31, k=(lane>>5)*8+j (8 contiguous k per lane)
// B[k][n]: n=lane&31, k=(lane>>5)*8+j
// C/D:     col=lane&31, row=(reg&3)+8*(reg>>2)+4*(lane>>5)

__device__ __forceinline__ u32 pack2(float a, float b) {
    half2v h; h[0] = (_Float16)a; h[1] = (_Float16)b;
    return __builtin_bit_cast(u32, h);
}
__device__ __forceinline__ half8 mk8(u32 a, u32 b, u32 c, u32 d) {
    uint4 t = make_uint4(a, b, c, d);
    return __builtin_bit_cast(half8, t);
}
__device__ __forceinline__ half8 cvt8(const float* __restrict__ p) {
    float4 u = *(const float4*)p;
    float4 v = *(const float4*)(p + 4);
    return mk8(pack2(u.x, u.y), pack2(u.z, u.w), pack2(v.x, v.y), pack2(v.z, v.w));
}
__device__ __forceinline__ half8 cvt8v(float4 u, float4 v) {
    return mk8(pack2(u.x, u.y), pack2(u.z, u.w), pack2(v.x, v.y), pack2(v.z, v.w));
}

// relu + f16-pack + lane^32 exchange: one C tile -> two B-frags (k-halves) for
// the NEXT transposed GEMM (contraction over this tile's 32 rows).
__device__ __forceinline__ void xform_tile(const f32x16& t, int hv, half8& f0, half8& f1) {
    u32 p[8], rp[8];
    #pragma unroll
    for (int q = 0; q < 8; ++q) p[q] = pack2(fmaxf(t[2*q], 0.f), fmaxf(t[2*q+1], 0.f));
    #pragma unroll
    for (int q = 0; q < 8; ++q) rp[q] = (u32)__shfl_xor((int)p[q], 32, 64);
    f0 = hv ? mk8(rp[2], rp[3], p[2], p[3]) : mk8(p[0], p[1], rp[0], rp[1]);
    f1 = hv ? mk8(rp[6], rp[7], p[6], p[7]) : mk8(p[4], p[5], rp[4], rp[5]);
}

// bias tile (same for both nt tiles of a given mt) from the permuted table
__device__ __forceinline__ f32x16 ldbias(const float* __restrict__ tbf, int hv, int mt) {
    const float4* p = (const float4*)tbf + hv*8 + mt*4;
    f32x16 r;
    #pragma unroll
    for (int q = 0; q < 4; ++q) {
        float4 v = p[q];
        r[4*q] = v.x; r[4*q+1] = v.y; r[4*q+2] = v.z; r[4*q+3] = v.w;
    }
    return r;
}

// ================= K1: weight/bias reorder into ws =================
// ws halves: w1f[2][8][64][8] | w2f[2][4][64][8] | wa1lowf | wa1upf | wa2f
// then f32 @ byte 49152: b1p[64] b2p[64] ba1p[64] ba2p[64] wa3p[64]
__global__ void uv_prep(const float* __restrict__ w1, const float* __restrict__ w2,
                        const float* __restrict__ wa1, const float* __restrict__ wa2,
                        const float* __restrict__ b1, const float* __restrict__ b2,
                        const float* __restrict__ ba1, const float* __restrict__ ba2,
                        const float* __restrict__ wa3,
                        _Float16* __restrict__ wsh, float* __restrict__ tbf) {
    const int idx = blockIdx.x * 256 + threadIdx.x;   // grid 96 -> idx < 24576
    const int j = idx & 7, lane = (idx >> 3) & 63;
    const int hv = lane >> 5, m31 = lane & 31;
    float v;
    if (idx < 8192)       { const int ks = (idx >> 9) & 7, mt = (idx >> 12) & 1;
        v = w1 [(ks*16 + hv*8 + j)*64 + mt*32 + m31]; }
    else if (idx < 12288) { const int ks = (idx >> 9) & 3, mt = (idx >> 11) & 1;
        v = w2 [(ks*16 + hv*8 + j)*64 + mt*32 + m31]; }
    else if (idx < 16384) { const int ks = (idx >> 9) & 3, mt = (idx >> 11) & 1;
        v = wa1[(ks*16 + hv*8 + j)*64 + mt*32 + m31]; }
    else if (idx < 20480) { const int ks = (idx >> 9) & 3, mt = (idx >> 11) & 1;
        v = wa1[(64 + ks*16 + hv*8 + j)*64 + mt*32 + m31]; }
    else                  { const int ks = (idx >> 9) & 3, mt = (idx >> 11) & 1;
        v = wa2[(ks*16 + hv*8 + j)*64 + mt*32 + m31]; }
    wsh[idx] = (_Float16)v;

    if (blockIdx.x == 0 && threadIdx.x < 64) {
        const int t = threadIdx.x;
        const int thv = t >> 5, r = t & 31, mt = r >> 4, i = r & 15;
        const int feat = mt*32 + (i & 3) + 8*(i >> 2) + 4*thv;
        tbf[t]       = b1[feat];
        tbf[64 + t]  = b2[feat];
        tbf[128 + t] = ba1[feat];
        tbf[192 + t] = ba2[feat];
        tbf[256 + t] = wa3[feat];
    }
}

// ================= K2: fused forward, ONE WAVE per block, TWO NODES per wave ===
// Two independent node-streams share every weight-fragment load (G8 feeds 8
// MFMAs instead of 4: halves L2 weight traffic, doubles per-wave ILP).
// Register discipline for <=256 VGPR (2 waves/SIMD):
//   - chunk2 loads deferred to after ks0/ks1, covered by the rating K-steps
//   - att1 is mt-sequential (64-reg accumulator set instead of 128)
//   - u-broadcast frags converted per-ks (transient, not held)
__global__ __launch_bounds__(64, 2) void uv_main(
    const int*   __restrict__ nodes,
    const int*   __restrict__ huv,
    const int*   __restrict__ hr,
    const float* __restrict__ v2e,
    const float* __restrict__ u2e,
    const float* __restrict__ r2e,
    const _Float16* __restrict__ wsh,
    const float* __restrict__ tbf,
    float*       __restrict__ out) {
    __shared__ float4 stage[2][520];         // per-node: 8 planes x 65 units (16B)
    const int lane = threadIdx.x;
    const int b0 = blockIdx.x * 2;
    const int n = lane & 31, hv = lane >> 5;

    // weight frag fetch: section base (in halves) + frag index
    #define G8(base, f) (*(const half8*)(wsh + (base) + (size_t)((f)*64 + lane)*8))

    // ---- staging indices: lane loads piece qq of rows t = j*8+tg, j=0..7
    const int tg = lane >> 3;                // row-in-group 0..7
    const int qq = lane & 7;                 // 16B piece within 128B chunk
    int rowid[2][8];
    #pragma unroll
    for (int u = 0; u < 2; ++u)
        #pragma unroll
        for (int j = 0; j < 8; ++j) {
            int t = j*8 + tg; if (t > LH-1) t = LH-1;
            rowid[u][j] = huv[(b0 + u)*LH + t];
        }
    // chunk1 (first 128B of each row) for both nodes (64 VGPR, freed at stage)
    float4 c1[2][8];
    #pragma unroll
    for (int u = 0; u < 2; ++u)
        #pragma unroll
        for (int j = 0; j < 8; ++j)
            c1[u][j] = *(const float4*)(v2e + (size_t)rowid[u][j]*D + qq*4);

    // ---- r2e token gathers stay direct (only 5 distinct rows -> line-shared)
    const int t1 = (32 + n < LH) ? 32 + n : LH - 1;
    const float* xr0[2]; const float* xr1[2];
    #pragma unroll
    for (int u = 0; u < 2; ++u) {
        const int ir0 = __builtin_nontemporal_load(hr + (b0 + u)*LH + n);
        const int ir1 = __builtin_nontemporal_load(hr + (b0 + u)*LH + t1);
        xr0[u] = r2e + (size_t)ir0 * D + hv*8;
        xr1[u] = r2e + (size_t)ir1 * D + hv*8;
    }
    // ---- u-row pointers (wave-uniform -> s_load); frags converted in att1
    const float* urow[2];
    #pragma unroll
    for (int u = 0; u < 2; ++u)
        urow[u] = u2e + (size_t)nodes[b0 + u] * D + hv*8;

    // stage chunk1 for both nodes
    #pragma unroll
    for (int u = 0; u < 2; ++u)
        #pragma unroll
        for (int j = 0; j < 8; ++j) stage[u][qq*65 + j*8 + tg] = c1[u][j];

    // ======== layer 1 (transposed): H[feat][tok] = W1^T @ X^T + b1
    f32x16 acc[2][4];                        // [node][a00,a01,a10,a11]
    {   // ks = 0 (bias as MFMA C)
        const f32x16 bc0 = ldbias(tbf, hv, 0), bc1 = ldbias(tbf, hv, 1);
        half8 w0 = G8(0, 0), w1f = G8(0, 8);
        #pragma unroll
        for (int u = 0; u < 2; ++u) {
            const int p0 = hv*2;
            half8 bf0 = cvt8v(stage[u][p0*65 + n],      stage[u][(p0+1)*65 + n]);
            half8 bf1 = cvt8v(stage[u][p0*65 + 32 + n], stage[u][(p0+1)*65 + 32 + n]);
            acc[u][0] = MFMA(w0,  bf0, bc0); acc[u][1] = MFMA(w0,  bf1, bc0);
            acc[u][2] = MFMA(w1f, bf0, bc1); acc[u][3] = MFMA(w1f, bf1, bc1);
        }
    }
    {   // ks = 1
        half8 w0 = G8(0, 1), w1f = G8(0, 9);
        #pragma unroll
        for (int u = 0; u < 2; ++u) {
            const int p0 = 4 + hv*2;
            half8 bf0 = cvt8v(stage[u][p0*65 + n],      stage[u][(p0+1)*65 + n]);
            half8 bf1 = cvt8v(stage[u][p0*65 + 32 + n], stage[u][(p0+1)*65 + 32 + n]);
            acc[u][0] = MFMA(w0,  bf0, acc[u][0]); acc[u][1] = MFMA(w0,  bf1, acc[u][1]);
            acc[u][2] = MFMA(w1f, bf0, acc[u][2]); acc[u][3] = MFMA(w1f, bf1, acc[u][3]);
        }
    }
    // issue chunk2 loads now (latency covered by the rating K-steps below)
    float4 c2[2][8];
    #pragma unroll
    for (int u = 0; u < 2; ++u)
        #pragma unroll
        for (int j = 0; j < 8; ++j)
            c2[u][j] = *(const float4*)(v2e + (size_t)rowid[u][j]*D + 32 + qq*4);
    // rating half first (K accumulation order is commutative)
    #pragma unroll
    for (int ks = 4; ks < 8; ++ks) {
        half8 w0 = G8(0, ks), w1f = G8(0, 8 + ks);
        #pragma unroll
        for (int u = 0; u < 2; ++u) {
            half8 bf0 = cvt8(xr0[u] + (ks - 4)*16);
            half8 bf1 = cvt8(xr1[u] + (ks - 4)*16);
            acc[u][0] = MFMA(w0,  bf0, acc[u][0]); acc[u][1] = MFMA(w0,  bf1, acc[u][1]);
            acc[u][2] = MFMA(w1f, bf0, acc[u][2]); acc[u][3] = MFMA(w1f, bf1, acc[u][3]);
        }
    }
    // stage chunk2 into the same planes (WAR safe: per-wave DS ops in-order)
    #pragma unroll
    for (int u = 0; u < 2; ++u)
        #pragma unroll
        for (int j = 0; j < 8; ++j) stage[u][qq*65 + j*8 + tg] = c2[u][j];
    #pragma unroll
    for (int ks = 2; ks < 4; ++ks) {
        half8 w0 = G8(0, ks), w1f = G8(0, 8 + ks);
        #pragma unroll
        for (int u = 0; u < 2; ++u) {
            const int p0 = (ks - 2)*4 + hv*2;
            half8 bf0 = cvt8v(stage[u][p0*65 + n],      stage[u][(p0+1)*65 + n]);
            half8 bf1 = cvt8v(stage[u][p0*65 + 32 + n], stage[u][(p0+1)*65 + 32 + n]);
            acc[u][0] = MFMA(w0,  bf0, acc[u][0]); acc[u][1] = MFMA(w0,  bf1, acc[u][1]);
            acc[u][2] = MFMA(w1f, bf0, acc[u][2]); acc[u][3] = MFMA(w1f, bf1, acc[u][3]);
        }
    }
    half8 hf[2][2][4];                       // [node][nt][k-frag]
    #pragma unroll
    for (int u = 0; u < 2; ++u) {
        xform_tile(acc[u][0], hv, hf[u][0][0], hf[u][0][1]);
        xform_tile(acc[u][1], hv, hf[u][1][0], hf[u][1][1]);
        xform_tile(acc[u][2], hv, hf[u][0][2], hf[u][0][3]);
        xform_tile(acc[u][3], hv, hf[u][1][2], hf[u][1][3]);
    }

    // ======== layer 2: O[feat][tok] = W2^T @ H + b2
    {
        const f32x16 bc0 = ldbias(tbf + 64, hv, 0), bc1 = ldbias(tbf + 64, hv, 1);
        half8 w0 = G8(8192, 0), w1f = G8(8192, 4);
        #pragma unroll
        for (int u = 0; u < 2; ++u) {
            acc[u][0] = MFMA(w0,  hf[u][0][0], bc0); acc[u][1] = MFMA(w0,  hf[u][1][0], bc0);
            acc[u][2] = MFMA(w1f, hf[u][0][0], bc1); acc[u][3] = MFMA(w1f, hf[u][1][0], bc1);
        }
    }
    #pragma unroll
    for (int ks = 1; ks < 4; ++ks) {
        half8 w0 = G8(8192, ks), w1f = G8(8192, 4 + ks);
        #pragma unroll
        for (int u = 0; u < 2; ++u) {
            acc[u][0] = MFMA(w0,  hf[u][0][ks], acc[u][0]); acc[u][1] = MFMA(w0,  hf[u][1][ks], acc[u][1]);
            acc[u][2] = MFMA(w1f, hf[u][0][ks], acc[u][2]); acc[u][3] = MFMA(w1f, hf[u][1][ks], acc[u][3]);
        }
    }
    half8 of[2][2][4];                       // O frags: feed att1 AND the epilogue
    #pragma unroll
    for (int u = 0; u < 2; ++u) {
        xform_tile(acc[u][0], hv, of[u][0][0], of[u][0][1]);
        xform_tile(acc[u][1], hv, of[u][1][0], of[u][1][1]);
        xform_tile(acc[u][2], hv, of[u][0][2], of[u][0][3]);
        xform_tile(acc[u][3], hv, of[u][1][2], of[u][1][3]);
    }

    // ======== att1: A1 = relu(Wa1low^T @ O + Wa1up^T @ u_bcast + ba1)
    // mt-sequential: halves the accumulator set vs the 1-node kernel's layout
    half8 af[2][2][4];
    #pragma unroll
    for (int mt = 0; mt < 2; ++mt) {
        f32x16 t0[2], t1v[2];                // [node], this mt's (nt0,nt1) tiles
        {
            const f32x16 bc = ldbias(tbf + 128, hv, mt);
            half8 w = G8(12288, mt*4 + 0);
            #pragma unroll
            for (int u = 0; u < 2; ++u) {
                t0[u]  = MFMA(w, of[u][0][0], bc);
                t1v[u] = MFMA(w, of[u][1][0], bc);
            }
        }
        #pragma unroll
        for (int ks = 1; ks < 4; ++ks) {
            half8 w = G8(12288, mt*4 + ks);
            #pragma unroll
            for (int u = 0; u < 2; ++u) {
                t0[u]  = MFMA(w, of[u][0][ks], t0[u]);
                t1v[u] = MFMA(w, of[u][1][ks], t1v[u]);
            }
        }
        #pragma unroll
        for (int ks = 0; ks < 4; ++ks) {     // u K-extension (same B for both nt)
            half8 w = G8(16384, mt*4 + ks);
            #pragma unroll
            for (int u = 0; u < 2; ++u) {
                half8 ufk = cvt8(urow[u] + ks*16);   // transient, L1-hot
                t0[u]  = MFMA(w, ufk, t0[u]);
                t1v[u] = MFMA(w, ufk, t1v[u]);
            }
        }
        #pragma unroll
        for (int u = 0; u < 2; ++u) {
            xform_tile(t0[u],  hv, af[u][0][mt*2], af[u][0][mt*2 + 1]);
            xform_tile(t1v[u], hv, af[u][1][mt*2], af[u][1][mt*2 + 1]);
        }
    }

    // ======== att2 + logits (mt sequential; bias via MFMA C)
    float lgs0[2] = {0.f, 0.f}, lgs1[2] = {0.f, 0.f};
    #pragma unroll
    for (int mt = 0; mt < 2; ++mt) {
        f32x16 c0[2], c1v[2];
        {
            const f32x16 bc = ldbias(tbf + 192, hv, mt);
            half8 w = G8(20480, mt*4 + 0);
            #pragma unroll
            for (int u = 0; u < 2; ++u) {
                c0[u]  = MFMA(w, af[u][0][0], bc);
                c1v[u] = MFMA(w, af[u][1][0], bc);
            }
        }
        #pragma unroll
        for (int ks = 1; ks < 4; ++ks) {
            half8 w = G8(20480, mt*4 + ks);
            #pragma unroll
            for (int u = 0; u < 2; ++u) {
                c0[u]  = MFMA(w, af[u][0][ks], c0[u]);
                c1v[u] = MFMA(w, af[u][1][ks], c1v[u]);
            }
        }
        #pragma unroll
        for (int q = 0; q < 4; ++q) {
            float4 w3 = ((const float4*)(tbf + 256))[hv*8 + mt*4 + q];
            #pragma unroll
            for (int u = 0; u < 2; ++u) {
                lgs0[u] += fmaxf(c0[u][4*q], 0.f)*w3.x + fmaxf(c0[u][4*q+1], 0.f)*w3.y
                         + fmaxf(c0[u][4*q+2], 0.f)*w3.z + fmaxf(c0[u][4*q+3], 0.f)*w3.w;
                lgs1[u] += fmaxf(c1v[u][4*q], 0.f)*w3.x + fmaxf(c1v[u][4*q+1], 0.f)*w3.y
                         + fmaxf(c1v[u][4*q+2], 0.f)*w3.z + fmaxf(c1v[u][4*q+3], 0.f)*w3.w;
            }
        }
    }

    // ======== softmax + epilogue, per node (of[u] dies after its store) ========
    #pragma unroll
    for (int u = 0; u < 2; ++u) {
        float lg0 = lgs0[u], lg1 = lgs1[u];
        // combine feat-halves across lane^32: lane holds logits of tokens n, n+32
        lg0 += __shfl_xor(lg0, 32, 64);
        lg1 += __shfl_xor(lg1, 32, 64);
        if (32 + n >= LH) lg1 = -1e30f;

        // softmax over 64 tokens (butterfly over the 32 token-lanes)
        float mx = fmaxf(lg0, lg1);
        #pragma unroll
        for (int off = 16; off >= 1; off >>= 1) mx = fmaxf(mx, __shfl_xor(mx, off, 64));
        const float e0 = __expf(lg0 - mx);
        const float e1 = __expf(lg1 - mx);   // masked token: exp(-huge)=0
        float s = e0 + e1;
        #pragma unroll
        for (int off = 16; off >= 1; off >>= 1) s += __shfl_xor(s, off, 64);
        const float at0 = e0 / s, at1 = e1 / s;

        // out[feat] = sum_tok att[tok]*O[feat][tok]
        float cur[32];
        #pragma unroll
        for (int ks = 0; ks < 4; ++ks)
            #pragma unroll
            for (int j = 0; j < 8; ++j)
                cur[ks*8 + j] = at0 * (float)of[u][0][ks][j] + at1 * (float)of[u][1][ks][j];
        // recursive-halving reduce-scatter over the 32 token-lanes
        #pragma unroll
        for (int k = 0; k < 5; ++k) {
            const int d = 1 << k, mybit = (lane >> k) & 1, half = 16 >> k;
            #pragma unroll
            for (int j2 = 0; j2 < 16; ++j2) {
                if (j2 < half) {
                    float sel  = mybit ? cur[2*j2]     : cur[2*j2 + 1];
                    float got  = __shfl_xor(sel, d, 64);
                    float keep = mybit ? cur[2*j2 + 1] : cur[2*j2];
                    cur[j2] = keep + got;
                }
            }
        }
        // lane owns feat = [bits: lane4 lane3 | hv | lane2 lane1 lane0]
        const int feat = ((lane >> 3) & 3)*16 + hv*8 + (lane & 7);
        __builtin_nontemporal_store(cur[0], out + (size_t)(b0 + u) * D + feat);
    }
    #undef G8
}

extern "C" void kernel_launch(void* const* d_in, const int* in_sizes, int n_in,
                              void* d_out, int out_size, void* d_ws, size_t ws_size,
                              hipStream_t stream) {
    const int*   nodes      = (const int*)  d_in[0];
    const int*   history_uv = (const int*)  d_in[1];
    const int*   history_r  = (const int*)  d_in[2];
    const float* v2e        = (const float*)d_in[3];
    const float* u2e        = (const float*)d_in[4];
    const float* r2e        = (const float*)d_in[5];
    const float* w1         = (const float*)d_in[6];
    const float* b1         = (const float*)d_in[7];
    const float* w2         = (const float*)d_in[8];
    const float* b2         = (const float*)d_in[9];
    const float* wa1        = (const float*)d_in[10];
    const float* ba1        = (const float*)d_in[11];
    const float* wa2        = (const float*)d_in[12];
    const float* ba2        = (const float*)d_in[13];
    const float* wa3        = (const float*)d_in[14];
    float* out = (float*)d_out;

    _Float16* wsh = (_Float16*)d_ws;
    float*    tbf = (float*)((char*)d_ws + 49152);

    uv_prep<<<96, 256, 0, stream>>>(w1, w2, wa1, wa2, b1, b2, ba1, ba2, wa3, wsh, tbf);
    uv_main<<<NB/2, 64, 0, stream>>>(nodes, history_uv, history_r,
                                     v2e, u2e, r2e, wsh, tbf, out);
}

// Round 2
// 221.021 us; speedup vs baseline: 1.0944x; 1.0944x over previous
//
#include <hip/hip_runtime.h>
#include <math.h>

#define NB 16384
#define LH 50
#define D  64

typedef _Float16 half2v __attribute__((ext_vector_type(2)));
typedef _Float16 half8  __attribute__((ext_vector_type(8)));
typedef float    f32x16 __attribute__((ext_vector_type(16)));
typedef unsigned int u32;

#define MFMA(a, b, c) __builtin_amdgcn_mfma_f32_32x32x16_f16((a), (b), (c), 0, 0, 0)

// ---- fragment facts (32x32x16, verified m74/m101 + R3..R5 pass) ----
// A[m][k]: m=lane&31, k=(lane>>5)*8+j (8 contiguous k per lane)
// B[k][n]: n=lane&31, k=(lane>>5)*8+j
// C/D:     col=lane&31, row=(reg&3)+8*(reg>>2)+4*(lane>>5)

__device__ __forceinline__ u32 pack2(float a, float b) {
    half2v h; h[0] = (_Float16)a; h[1] = (_Float16)b;
    return __builtin_bit_cast(u32, h);
}
__device__ __forceinline__ half8 mk8(u32 a, u32 b, u32 c, u32 d) {
    uint4 t = make_uint4(a, b, c, d);
    return __builtin_bit_cast(half8, t);
}
__device__ __forceinline__ half8 cvt8(const float* __restrict__ p) {
    float4 u = *(const float4*)p;
    float4 v = *(const float4*)(p + 4);
    return mk8(pack2(u.x, u.y), pack2(u.z, u.w), pack2(v.x, v.y), pack2(v.z, v.w));
}
__device__ __forceinline__ half8 cvt8v(float4 u, float4 v) {
    return mk8(pack2(u.x, u.y), pack2(u.z, u.w), pack2(v.x, v.y), pack2(v.z, v.w));
}

// relu + f16-pack + lane^32 exchange: one C tile -> two B-frags (k-halves) for
// the NEXT transposed GEMM (contraction over this tile's 32 rows).
__device__ __forceinline__ void xform_tile(const f32x16& t, int hv, half8& f0, half8& f1) {
    u32 p[8], rp[8];
    #pragma unroll
    for (int q = 0; q < 8; ++q) p[q] = pack2(fmaxf(t[2*q], 0.f), fmaxf(t[2*q+1], 0.f));
    #pragma unroll
    for (int q = 0; q < 8; ++q) rp[q] = (u32)__shfl_xor((int)p[q], 32, 64);
    f0 = hv ? mk8(rp[2], rp[3], p[2], p[3]) : mk8(p[0], p[1], rp[0], rp[1]);
    f1 = hv ? mk8(rp[6], rp[7], p[6], p[7]) : mk8(p[4], p[5], rp[4], rp[5]);
}

// bias tile (same for both nt tiles of a given mt) from the permuted table
__device__ __forceinline__ f32x16 ldbias(const float* __restrict__ tbf, int hv, int mt) {
    const float4* p = (const float4*)tbf + hv*8 + mt*4;
    f32x16 r;
    #pragma unroll
    for (int q = 0; q < 4; ++q) {
        float4 v = p[q];
        r[4*q] = v.x; r[4*q+1] = v.y; r[4*q+2] = v.z; r[4*q+3] = v.w;
    }
    return r;
}

// ================= K1: weight/bias reorder into ws =================
// ws halves: w1f[2][8][64][8] | w2f[2][4][64][8] | wa1lowf | wa1upf | wa2f
// then f32 @ byte 49152: b1p[64] b2p[64] ba1p[64] ba2p[64] wa3p[64]
__global__ void uv_prep(const float* __restrict__ w1, const float* __restrict__ w2,
                        const float* __restrict__ wa1, const float* __restrict__ wa2,
                        const float* __restrict__ b1, const float* __restrict__ b2,
                        const float* __restrict__ ba1, const float* __restrict__ ba2,
                        const float* __restrict__ wa3,
                        _Float16* __restrict__ wsh, float* __restrict__ tbf) {
    const int idx = blockIdx.x * 256 + threadIdx.x;   // grid 96 -> idx < 24576
    const int j = idx & 7, lane = (idx >> 3) & 63;
    const int hv = lane >> 5, m31 = lane & 31;
    float v;
    if (idx < 8192)       { const int ks = (idx >> 9) & 7, mt = (idx >> 12) & 1;
        v = w1 [(ks*16 + hv*8 + j)*64 + mt*32 + m31]; }
    else if (idx < 12288) { const int ks = (idx >> 9) & 3, mt = (idx >> 11) & 1;
        v = w2 [(ks*16 + hv*8 + j)*64 + mt*32 + m31]; }
    else if (idx < 16384) { const int ks = (idx >> 9) & 3, mt = (idx >> 11) & 1;
        v = wa1[(ks*16 + hv*8 + j)*64 + mt*32 + m31]; }
    else if (idx < 20480) { const int ks = (idx >> 9) & 3, mt = (idx >> 11) & 1;
        v = wa1[(64 + ks*16 + hv*8 + j)*64 + mt*32 + m31]; }
    else                  { const int ks = (idx >> 9) & 3, mt = (idx >> 11) & 1;
        v = wa2[(ks*16 + hv*8 + j)*64 + mt*32 + m31]; }
    wsh[idx] = (_Float16)v;

    if (blockIdx.x == 0 && threadIdx.x < 64) {
        const int t = threadIdx.x;
        const int thv = t >> 5, r = t & 31, mt = r >> 4, i = r & 15;
        const int feat = mt*32 + (i & 3) + 8*(i >> 2) + 4*thv;
        tbf[t]       = b1[feat];
        tbf[64 + t]  = b2[feat];
        tbf[128 + t] = ba1[feat];
        tbf[192 + t] = ba2[feat];
        tbf[256 + t] = wa3[feat];
    }
}

// ================= K2: fused forward, FOUR INDEPENDENT WAVES per block =========
// Round-0 per-wave structure (1 node/wave, proven 143 us) packed 4 waves to a
// 256-thread workgroup to beat the ~8-workgroups/CU residency cap (both prior
// rounds pinned at ~22% occupancy with 1-wave blocks despite LDS/VGPR slack).
// Waves are fully independent: private stage slice, no __syncthreads anywhere.
__global__ __launch_bounds__(256) void uv_main(
    const int*   __restrict__ nodes,
    const int*   __restrict__ huv,
    const int*   __restrict__ hr,
    const float* __restrict__ v2e,
    const float* __restrict__ u2e,
    const float* __restrict__ r2e,
    const _Float16* __restrict__ wsh,
    const float* __restrict__ tbf,
    float*       __restrict__ out) {
    __shared__ float4 stage[4][520];         // per-wave: 8 planes x 65 units (16B)
    const int lane = threadIdx.x & 63;
    const int w = threadIdx.x >> 6;          // wave id within block
    const int b = blockIdx.x * 4 + w;        // node id
    const int n = lane & 31, hv = lane >> 5;
    float4* const stg = stage[w];

    // weight frag fetch: section base (in halves) + frag index
    #define G8(base, f) (*(const half8*)(wsh + (base) + (size_t)((f)*64 + lane)*8))

    // ---- staging indices: lane loads piece qq of rows t = j*8+tg, j=0..7
    const int tg = lane >> 3;                // row-in-group 0..7
    const int qq = lane & 7;                 // 16B piece within 128B chunk
    int rowid[8];
    #pragma unroll
    for (int j = 0; j < 8; ++j) {
        int t = j*8 + tg; if (t > LH-1) t = LH-1;
        rowid[j] = huv[b*LH + t];
    }
    // issue both 8 KB chunks' loads up-front (coalesced: 8 lanes span 128B/row)
    float4 c1[8], c2[8];
    #pragma unroll
    for (int j = 0; j < 8; ++j)
        c1[j] = *(const float4*)(v2e + (size_t)rowid[j]*D + qq*4);
    #pragma unroll
    for (int j = 0; j < 8; ++j)
        c2[j] = *(const float4*)(v2e + (size_t)rowid[j]*D + 32 + qq*4);

    // ---- r2e token gathers stay direct (only 5 distinct rows -> line-shared)
    const int t1  = (32 + n < LH) ? 32 + n : LH - 1;
    const int ir0 = __builtin_nontemporal_load(hr + b*LH + n);
    const int ir1 = __builtin_nontemporal_load(hr + b*LH + t1);
    const float* xr0 = r2e + (size_t)ir0 * D + hv*8;
    const float* xr1 = r2e + (size_t)ir1 * D + hv*8;

    // ---- u-broadcast B-frags for att1's K-extension (u row wave-uniform -> s_load)
    const float* urow = u2e + (size_t)nodes[b] * D + hv*8;
    half8 uf[4];
    #pragma unroll
    for (int ks = 0; ks < 4; ++ks) uf[ks] = cvt8(urow + ks*16);

    // ======== layer 1 (transposed): H[feat][tok] = W1^T @ X^T + b1
    f32x16 a00, a01, a10, a11;
    // stage chunk1 (pieces 0..7 = ks 0,1)
    #pragma unroll
    for (int j = 0; j < 8; ++j) stg[qq*65 + j*8 + tg] = c1[j];
    {   // ks = 0 (bias as MFMA C)
        const f32x16 bc0 = ldbias(tbf, hv, 0), bc1 = ldbias(tbf, hv, 1);
        const int p0 = hv*2;
        half8 bf0 = cvt8v(stg[p0*65 + n],      stg[(p0+1)*65 + n]);
        half8 bf1 = cvt8v(stg[p0*65 + 32 + n], stg[(p0+1)*65 + 32 + n]);
        half8 w0 = G8(0, 0), w1f = G8(0, 8);
        a00 = MFMA(w0, bf0, bc0);  a01 = MFMA(w0, bf1, bc0);
        a10 = MFMA(w1f, bf0, bc1); a11 = MFMA(w1f, bf1, bc1);
    }
    {   // ks = 1
        const int p0 = 4 + hv*2;
        half8 bf0 = cvt8v(stg[p0*65 + n],      stg[(p0+1)*65 + n]);
        half8 bf1 = cvt8v(stg[p0*65 + 32 + n], stg[(p0+1)*65 + 32 + n]);
        half8 w0 = G8(0, 1), w1f = G8(0, 9);
        a00 = MFMA(w0, bf0, a00);  a01 = MFMA(w0, bf1, a01);
        a10 = MFMA(w1f, bf0, a10); a11 = MFMA(w1f, bf1, a11);
    }
    // stage chunk2 (pieces 8..15 = ks 2,3) into the same planes (WAR: DS in-order)
    #pragma unroll
    for (int j = 0; j < 8; ++j) stg[qq*65 + j*8 + tg] = c2[j];
    #pragma unroll
    for (int ks = 2; ks < 4; ++ks) {
        const int p0 = (ks - 2)*4 + hv*2;
        half8 bf0 = cvt8v(stg[p0*65 + n],      stg[(p0+1)*65 + n]);
        half8 bf1 = cvt8v(stg[p0*65 + 32 + n], stg[(p0+1)*65 + 32 + n]);
        half8 w0 = G8(0, ks), w1f = G8(0, 8 + ks);
        a00 = MFMA(w0, bf0, a00);  a01 = MFMA(w0, bf1, a01);
        a10 = MFMA(w1f, bf0, a10); a11 = MFMA(w1f, bf1, a11);
    }
    #pragma unroll
    for (int ks = 4; ks < 8; ++ks) {          // rating half: direct gathers
        half8 bf0 = cvt8(xr0 + (ks - 4)*16);
        half8 bf1 = cvt8(xr1 + (ks - 4)*16);
        half8 w0 = G8(0, ks), w1f = G8(0, 8 + ks);
        a00 = MFMA(w0, bf0, a00);  a01 = MFMA(w0, bf1, a01);
        a10 = MFMA(w1f, bf0, a10); a11 = MFMA(w1f, bf1, a11);
    }
    half8 hf[2][4];                          // relu+exchange -> B-frags of H
    xform_tile(a00, hv, hf[0][0], hf[0][1]); xform_tile(a01, hv, hf[1][0], hf[1][1]);
    xform_tile(a10, hv, hf[0][2], hf[0][3]); xform_tile(a11, hv, hf[1][2], hf[1][3]);

    // ======== layer 2: O[feat][tok] = W2^T @ H + b2
    {
        const f32x16 bc0 = ldbias(tbf + 64, hv, 0), bc1 = ldbias(tbf + 64, hv, 1);
        half8 w0 = G8(8192, 0), w1f = G8(8192, 4);
        a00 = MFMA(w0, hf[0][0], bc0);  a01 = MFMA(w0, hf[1][0], bc0);
        a10 = MFMA(w1f, hf[0][0], bc1); a11 = MFMA(w1f, hf[1][0], bc1);
    }
    #pragma unroll
    for (int ks = 1; ks < 4; ++ks) {
        half8 w0 = G8(8192, ks), w1f = G8(8192, 4 + ks);
        a00 = MFMA(w0, hf[0][ks], a00);  a01 = MFMA(w0, hf[1][ks], a01);
        a10 = MFMA(w1f, hf[0][ks], a10); a11 = MFMA(w1f, hf[1][ks], a11);
    }
    half8 of[2][4];                          // O frags: feed att1 AND the epilogue
    xform_tile(a00, hv, of[0][0], of[0][1]); xform_tile(a01, hv, of[1][0], of[1][1]);
    xform_tile(a10, hv, of[0][2], of[0][3]); xform_tile(a11, hv, of[1][2], of[1][3]);

    // ======== att1: A1 = relu(Wa1low^T @ O + Wa1up^T @ u_bcast + ba1)
    {
        const f32x16 bc0 = ldbias(tbf + 128, hv, 0), bc1 = ldbias(tbf + 128, hv, 1);
        half8 w0 = G8(12288, 0), w1f = G8(12288, 4);
        a00 = MFMA(w0, of[0][0], bc0);  a01 = MFMA(w0, of[1][0], bc0);
        a10 = MFMA(w1f, of[0][0], bc1); a11 = MFMA(w1f, of[1][0], bc1);
    }
    #pragma unroll
    for (int ks = 1; ks < 4; ++ks) {
        half8 w0 = G8(12288, ks), w1f = G8(12288, 4 + ks);
        a00 = MFMA(w0, of[0][ks], a00);  a01 = MFMA(w0, of[1][ks], a01);
        a10 = MFMA(w1f, of[0][ks], a10); a11 = MFMA(w1f, of[1][ks], a11);
    }
    #pragma unroll
    for (int ks = 0; ks < 4; ++ks) {         // u K-extension (same B for both nt)
        half8 w0 = G8(16384, ks), w1f = G8(16384, 4 + ks);
        a00 = MFMA(w0, uf[ks], a00);  a01 = MFMA(w0, uf[ks], a01);
        a10 = MFMA(w1f, uf[ks], a10); a11 = MFMA(w1f, uf[ks], a11);
    }
    half8 af[2][4];
    xform_tile(a00, hv, af[0][0], af[0][1]); xform_tile(a01, hv, af[1][0], af[1][1]);
    xform_tile(a10, hv, af[0][2], af[0][3]); xform_tile(a11, hv, af[1][2], af[1][3]);

    // ======== att2 + logits (mt sequential; bias via MFMA C)
    float lg0 = 0.f, lg1 = 0.f;
    #pragma unroll
    for (int mt = 0; mt < 2; ++mt) {
        f32x16 c0, c1v;
        {
            const f32x16 bc = ldbias(tbf + 192, hv, mt);
            half8 wv = G8(20480, mt*4 + 0);
            c0  = MFMA(wv, af[0][0], bc);
            c1v = MFMA(wv, af[1][0], bc);
        }
        #pragma unroll
        for (int ks = 1; ks < 4; ++ks) {
            half8 wv = G8(20480, mt*4 + ks);
            c0  = MFMA(wv, af[0][ks], c0);
            c1v = MFMA(wv, af[1][ks], c1v);
        }
        #pragma unroll
        for (int q = 0; q < 4; ++q) {
            float4 w3 = ((const float4*)(tbf + 256))[hv*8 + mt*4 + q];
            lg0 += fmaxf(c0[4*q], 0.f)*w3.x + fmaxf(c0[4*q+1], 0.f)*w3.y
                 + fmaxf(c0[4*q+2], 0.f)*w3.z + fmaxf(c0[4*q+3], 0.f)*w3.w;
            lg1 += fmaxf(c1v[4*q], 0.f)*w3.x + fmaxf(c1v[4*q+1], 0.f)*w3.y
                 + fmaxf(c1v[4*q+2], 0.f)*w3.z + fmaxf(c1v[4*q+3], 0.f)*w3.w;
        }
    }
    // combine feat-halves across lane^32: each lane now holds logits of tokens n, n+32
    lg0 += __shfl_xor(lg0, 32, 64);
    lg1 += __shfl_xor(lg1, 32, 64);
    if (32 + n >= LH) lg1 = -1e30f;

    // ---- softmax over 64 tokens (butterfly over the 32 token-lanes)
    float mx = fmaxf(lg0, lg1);
    #pragma unroll
    for (int off = 16; off >= 1; off >>= 1) mx = fmaxf(mx, __shfl_xor(mx, off, 64));
    const float e0 = __expf(lg0 - mx);
    const float e1 = __expf(lg1 - mx);       // masked token: exp(-huge)=0
    float s = e0 + e1;
    #pragma unroll
    for (int off = 16; off >= 1; off >>= 1) s += __shfl_xor(s, off, 64);
    const float at0 = e0 / s, at1 = e1 / s;

    // ======== epilogue: out[feat] = sum_tok att[tok]*O[feat][tok]
    float cur[32];
    #pragma unroll
    for (int ks = 0; ks < 4; ++ks)
        #pragma unroll
        for (int j = 0; j < 8; ++j)
            cur[ks*8 + j] = at0 * (float)of[0][ks][j] + at1 * (float)of[1][ks][j];
    // recursive-halving reduce-scatter over the 32 token-lanes (5 levels, 31 shfl)
    #pragma unroll
    for (int k = 0; k < 5; ++k) {
        const int d = 1 << k, mybit = (lane >> k) & 1, half = 16 >> k;
        #pragma unroll
        for (int j2 = 0; j2 < 16; ++j2) {
            if (j2 < half) {
                float sel  = mybit ? cur[2*j2]     : cur[2*j2 + 1];
                float got  = __shfl_xor(sel, d, 64);
                float keep = mybit ? cur[2*j2 + 1] : cur[2*j2];
                cur[j2] = keep + got;
            }
        }
    }
    // lane owns feat = [bits: lane4 lane3 | hv | lane2 lane1 lane0]
    const int feat = ((lane >> 3) & 3)*16 + hv*8 + (lane & 7);
    __builtin_nontemporal_store(cur[0], out + (size_t)b * D + feat);
    #undef G8
}

extern "C" void kernel_launch(void* const* d_in, const int* in_sizes, int n_in,
                              void* d_out, int out_size, void* d_ws, size_t ws_size,
                              hipStream_t stream) {
    const int*   nodes      = (const int*)  d_in[0];
    const int*   history_uv = (const int*)  d_in[1];
    const int*   history_r  = (const int*)  d_in[2];
    const float* v2e        = (const float*)d_in[3];
    const float* u2e        = (const float*)d_in[4];
    const float* r2e        = (const float*)d_in[5];
    const float* w1         = (const float*)d_in[6];
    const float* b1         = (const float*)d_in[7];
    const float* w2         = (const float*)d_in[8];
    const float* b2         = (const float*)d_in[9];
    const float* wa1        = (const float*)d_in[10];
    const float* ba1        = (const float*)d_in[11];
    const float* wa2        = (const float*)d_in[12];
    const float* ba2        = (const float*)d_in[13];
    const float* wa3        = (const float*)d_in[14];
    float* out = (float*)d_out;

    _Float16* wsh = (_Float16*)d_ws;
    float*    tbf = (float*)((char*)d_ws + 49152);

    uv_prep<<<96, 256, 0, stream>>>(w1, w2, wa1, wa2, b1, b2, ba1, ba2, wa3, wsh, tbf);
    uv_main<<<NB/4, 256, 0, stream>>>(nodes, history_uv, history_r,
                                      v2e, u2e, r2e, wsh, tbf, out);
}

// Round 3
// 220.692 us; speedup vs baseline: 1.0961x; 1.0015x over previous
//
#include <hip/hip_runtime.h>
#include <math.h>

#define NB 16384
#define LH 50
#define D  64

// workspace layout (bytes):
//   0       : wsh   (f16 weight frags, 5 sections x 4096 halves = 40 KB)
//   49152   : tbf   (f32: b2p[64] ba2p[64] wa3p[64] ba1p[64] R1p[5][64] = 576 f)
//   65536   : UB    (f32 [16384][64] permuted, u@A1up + ba1, per node)
//   4259840 : P1p   (f32 [100000][64] permuted, v2e@W1_top, per item)
// total required: 4259840 + 25600000 = 29,859,840 B (~28.5 MB)
#define TBF_OFF 49152
#define UB_OFF  65536
#define P1_OFF  4259840

typedef _Float16 half2v __attribute__((ext_vector_type(2)));
typedef _Float16 half8  __attribute__((ext_vector_type(8)));
typedef float    f32x16 __attribute__((ext_vector_type(16)));
typedef unsigned int u32;

#define MFMA(a, b, c) __builtin_amdgcn_mfma_f32_32x32x16_f16((a), (b), (c), 0, 0, 0)

// ---- fragment facts (32x32x16, verified) ----
// A[m][k]: m=lane&31, k=(lane>>5)*8+j (8 contiguous k per lane)
// B[k][n]: n=lane&31, k=(lane>>5)*8+j
// C/D:     col=lane&31, row=(reg&3)+8*(reg>>2)+4*(lane>>5)
// permutation t(hv,mt,q) = hv*32+mt*16+q  <->  feat = mt*32+(q&3)+8*(q>>2)+4*hv

__device__ __forceinline__ u32 pack2(float a, float b) {
    half2v h; h[0] = (_Float16)a; h[1] = (_Float16)b;
    return __builtin_bit_cast(u32, h);
}
__device__ __forceinline__ half8 mk8(u32 a, u32 b, u32 c, u32 d) {
    uint4 t = make_uint4(a, b, c, d);
    return __builtin_bit_cast(half8, t);
}
__device__ __forceinline__ half8 cvt8(const float* __restrict__ p) {
    float4 u = *(const float4*)p;
    float4 v = *(const float4*)(p + 4);
    return mk8(pack2(u.x, u.y), pack2(u.z, u.w), pack2(v.x, v.y), pack2(v.z, v.w));
}
// relu(stage + rating-bias) -> B-frag (layer2 input built from f32 pre-acts)
__device__ __forceinline__ half8 relu8(float4 a, float4 b, float4 ra, float4 rb) {
    return mk8(pack2(fmaxf(a.x + ra.x, 0.f), fmaxf(a.y + ra.y, 0.f)),
               pack2(fmaxf(a.z + ra.z, 0.f), fmaxf(a.w + ra.w, 0.f)),
               pack2(fmaxf(b.x + rb.x, 0.f), fmaxf(b.y + rb.y, 0.f)),
               pack2(fmaxf(b.z + rb.z, 0.f), fmaxf(b.w + rb.w, 0.f)));
}

// relu + f16-pack + lane^32 exchange: one C tile -> two B-frags (k-halves)
__device__ __forceinline__ void xform_tile(const f32x16& t, int hv, half8& f0, half8& f1) {
    u32 p[8], rp[8];
    #pragma unroll
    for (int q = 0; q < 8; ++q) p[q] = pack2(fmaxf(t[2*q], 0.f), fmaxf(t[2*q+1], 0.f));
    #pragma unroll
    for (int q = 0; q < 8; ++q) rp[q] = (u32)__shfl_xor((int)p[q], 32, 64);
    f0 = hv ? mk8(rp[2], rp[3], p[2], p[3]) : mk8(p[0], p[1], rp[0], rp[1]);
    f1 = hv ? mk8(rp[6], rp[7], p[6], p[7]) : mk8(p[4], p[5], rp[4], rp[5]);
}

// bias/UB tile from a 64-float permuted row
__device__ __forceinline__ f32x16 ldbias(const float* __restrict__ tb, int hv, int mt) {
    const float4* p = (const float4*)tb + hv*8 + mt*4;
    f32x16 r;
    #pragma unroll
    for (int q = 0; q < 4; ++q) {
        float4 v = p[q];
        r[4*q] = v.x; r[4*q+1] = v.y; r[4*q+2] = v.z; r[4*q+3] = v.w;
    }
    return r;
}

__device__ __forceinline__ half8 g8(const _Float16* __restrict__ wsh, int base, int f, int lane) {
    return *(const half8*)(wsh + base + (size_t)(f*64 + lane)*8);
}

// ================= K1: weight/bias reorder =================
// wsh sections (4096 halves each, frag f = mt*4+ks):
//   @0     w2   A-frags, k-index pi-adjusted (H arrives feat-permuted)
//   @4096  wa1low A-frags (natural)
//   @8192  wa2  A-frags (natural)
//   @12288 w1_top A-frags for p1_prep (natural)
//   @16384 wa1up  A-frags for ub_prep (natural)
// tbf: [0]=b2p [64]=ba2p [128]=wa3p [192]=ba1p [256..575]=R1p[5][64]
__global__ void uv_prep(const float* __restrict__ w1, const float* __restrict__ w2,
                        const float* __restrict__ wa1, const float* __restrict__ wa2,
                        const float* __restrict__ r2e,
                        const float* __restrict__ b1, const float* __restrict__ b2,
                        const float* __restrict__ ba1, const float* __restrict__ ba2,
                        const float* __restrict__ wa3,
                        _Float16* __restrict__ wsh, float* __restrict__ tbf) {
    const int idx = blockIdx.x * 256 + threadIdx.x;   // grid 80 -> idx < 20480
    const int j = idx & 7, lane = (idx >> 3) & 63;
    const int hv = lane >> 5, m31 = lane & 31;
    const int f = (idx >> 9) & 7, ks = f & 3, mt = f >> 2;
    const int sec = idx >> 12;
    const int tau = ks*16 + hv*8 + j;
    float v;
    if (sec == 0) {       // w2 with k-permutation folded in
        const int thv = (tau >> 5) & 1, tmt = (tau >> 4) & 1, i = tau & 15;
        const int feat = tmt*32 + (i & 3) + 8*(i >> 2) + 4*thv;
        v = w2[feat*64 + mt*32 + m31];
    }
    else if (sec == 1) v = wa1[tau*64 + mt*32 + m31];
    else if (sec == 2) v = wa2[tau*64 + mt*32 + m31];
    else if (sec == 3) v = w1 [tau*64 + mt*32 + m31];
    else               v = wa1[(64 + tau)*64 + mt*32 + m31];
    wsh[idx] = (_Float16)v;

    if (blockIdx.x == 0 && threadIdx.x < 64) {
        const int t = threadIdx.x;
        const int thv = t >> 5, r = t & 31, mtt = r >> 4, i = r & 15;
        const int feat = mtt*32 + (i & 3) + 8*(i >> 2) + 4*thv;
        tbf[t]       = b2[feat];
        tbf[64 + t]  = ba2[feat];
        tbf[128 + t] = wa3[feat];
        tbf[192 + t] = ba1[feat];
    }
    if (blockIdx.x == 1 && threadIdx.x < 64) {
        // R1p[r][t] = (r2e[r] @ W1_bot)[feat(t)] + b1[feat(t)]  (f32 exact)
        const int t = threadIdx.x;
        const int thv = t >> 5, r5 = t & 31, mtt = r5 >> 4, i = r5 & 15;
        const int feat = mtt*32 + (i & 3) + 8*(i >> 2) + 4*thv;
        #pragma unroll 1
        for (int rr = 0; rr < 5; ++rr) {
            float acc = b1[feat];
            for (int k = 0; k < 64; ++k)
                acc += r2e[rr*64 + k] * w1[(64 + k)*64 + feat];
            tbf[256 + rr*64 + t] = acc;
        }
    }
}

// ================= K1b: P1 = v2e @ W1_top (permuted rows) =================
__global__ __launch_bounds__(256) void p1_prep(const float* __restrict__ v2e,
                                               const _Float16* __restrict__ wsh,
                                               float* __restrict__ P1p) {
    const int lane = threadIdx.x & 63;
    const int tile = blockIdx.x * 4 + (threadIdx.x >> 6);
    if (tile >= 3125) return;                 // 100000 / 32 tiles exactly
    const int n = lane & 31, hv = lane >> 5;
    const int item = tile*32 + n;

    half8 bf[4];
    #pragma unroll
    for (int ks = 0; ks < 4; ++ks)
        bf[ks] = cvt8(v2e + (size_t)item*64 + ks*16 + hv*8);
    f32x16 zz;
    #pragma unroll
    for (int q = 0; q < 16; ++q) zz[q] = 0.f;
    f32x16 a0 = MFMA(g8(wsh, 12288, 0, lane), bf[0], zz);
    f32x16 a1 = MFMA(g8(wsh, 12288, 4, lane), bf[0], zz);
    #pragma unroll
    for (int ks = 1; ks < 4; ++ks) {
        a0 = MFMA(g8(wsh, 12288, ks,     lane), bf[ks], a0);
        a1 = MFMA(g8(wsh, 12288, 4 + ks, lane), bf[ks], a1);
    }
    float4* dst = (float4*)(P1p + (size_t)item*64 + hv*32);
    #pragma unroll
    for (int q = 0; q < 4; ++q) {
        dst[q]     = make_float4(a0[4*q], a0[4*q+1], a0[4*q+2], a0[4*q+3]);
        dst[4 + q] = make_float4(a1[4*q], a1[4*q+1], a1[4*q+2], a1[4*q+3]);
    }
}

// ================= K1c: UB = u2e[nodes] @ A1_up + ba1 (permuted rows) =========
__global__ __launch_bounds__(256) void ub_prep(const int* __restrict__ nodes,
                                               const float* __restrict__ u2e,
                                               const _Float16* __restrict__ wsh,
                                               const float* __restrict__ tbf,
                                               float* __restrict__ UB) {
    const int lane = threadIdx.x & 63;
    const int tile = blockIdx.x * 4 + (threadIdx.x >> 6);   // 512 tiles exactly
    const int n = lane & 31, hv = lane >> 5;
    const int s = tile*32 + n;
    const int nid = nodes[s];

    half8 bf[4];
    #pragma unroll
    for (int ks = 0; ks < 4; ++ks)
        bf[ks] = cvt8(u2e + (size_t)nid*64 + ks*16 + hv*8);
    f32x16 a0 = ldbias(tbf + 192, hv, 0);     // ba1 permuted as C-init
    f32x16 a1 = ldbias(tbf + 192, hv, 1);
    #pragma unroll
    for (int ks = 0; ks < 4; ++ks) {
        a0 = MFMA(g8(wsh, 16384, ks,     lane), bf[ks], a0);
        a1 = MFMA(g8(wsh, 16384, 4 + ks, lane), bf[ks], a1);
    }
    float4* dst = (float4*)(UB + (size_t)s*64 + hv*32);
    #pragma unroll
    for (int q = 0; q < 4; ++q) {
        dst[q]     = make_float4(a0[4*q], a0[4*q+1], a0[4*q+2], a0[4*q+3]);
        dst[4 + q] = make_float4(a1[4*q], a1[4*q+1], a1[4*q+2], a1[4*q+3]);
    }
}

// ================= K2: fused forward (layer1 precomputed) =================
// 4 independent waves/block. Per node: gather P1p rows -> relu(P1+R1) -> 48
// MFMAs (layer2, att1 with UB C-init, att2) -> softmax -> epilogue.
__global__ __launch_bounds__(256) void uv_main(
    const int*   __restrict__ huv,
    const int*   __restrict__ hr,
    const float* __restrict__ P1p,
    const float* __restrict__ UB,
    const _Float16* __restrict__ wsh,
    const float* __restrict__ tbf,
    float*       __restrict__ out) {
    __shared__ float4 stage[4][520];         // per-wave: 8 planes x 65 units (16B)
    const int lane = threadIdx.x & 63;
    const int w = threadIdx.x >> 6;
    const int b = blockIdx.x * 4 + w;        // node id
    const int n = lane & 31, hv = lane >> 5;
    float4* const stg = stage[w];

    #define G8(base, f) g8(wsh, (base), (f), lane)

    // ---- staging indices: lane loads piece qq of rows t = j*8+tg
    const int tg = lane >> 3;
    const int qq = lane & 7;
    int rowid[8];
    #pragma unroll
    for (int j = 0; j < 8; ++j) {
        int t = j*8 + tg; if (t > LH-1) t = LH-1;
        rowid[j] = huv[b*LH + t];
    }
    float4 c1[8], c2[8];
    #pragma unroll
    for (int j = 0; j < 8; ++j)
        c1[j] = *(const float4*)(P1p + (size_t)rowid[j]*64 + qq*4);
    #pragma unroll
    for (int j = 0; j < 8; ++j)
        c2[j] = *(const float4*)(P1p + (size_t)rowid[j]*64 + 32 + qq*4);

    // ---- rating rows from the tiny R1p table (L1-hot, 1.25 KB)
    const int t1  = (32 + n < LH) ? 32 + n : LH - 1;
    const int ir0 = __builtin_nontemporal_load(hr + b*LH + n);
    const int ir1 = __builtin_nontemporal_load(hr + b*LH + t1);
    const float* xr0 = tbf + 256 + ir0*64 + hv*8;
    const float* xr1 = tbf + 256 + ir1*64 + hv*8;

    // ======== layer 2: O[feat][tok] = W2^T(pi) @ relu(P1+R1) + b2
    f32x16 a00, a01, a10, a11;
    #pragma unroll
    for (int j = 0; j < 8; ++j) stg[qq*65 + j*8 + tg] = c1[j];
    {   // ks = 0
        const f32x16 bc0 = ldbias(tbf, hv, 0), bc1 = ldbias(tbf, hv, 1);
        const int p0 = hv*2;
        float4 r00 = *(const float4*)(xr0), r01 = *(const float4*)(xr0 + 4);
        float4 r10 = *(const float4*)(xr1), r11 = *(const float4*)(xr1 + 4);
        half8 bf0 = relu8(stg[p0*65 + n],      stg[(p0+1)*65 + n],      r00, r01);
        half8 bf1 = relu8(stg[p0*65 + 32 + n], stg[(p0+1)*65 + 32 + n], r10, r11);
        half8 w0 = G8(0, 0), w1f = G8(0, 4);
        a00 = MFMA(w0, bf0, bc0);  a01 = MFMA(w0, bf1, bc0);
        a10 = MFMA(w1f, bf0, bc1); a11 = MFMA(w1f, bf1, bc1);
    }
    {   // ks = 1
        const int p0 = 4 + hv*2;
        float4 r00 = *(const float4*)(xr0 + 16), r01 = *(const float4*)(xr0 + 20);
        float4 r10 = *(const float4*)(xr1 + 16), r11 = *(const float4*)(xr1 + 20);
        half8 bf0 = relu8(stg[p0*65 + n],      stg[(p0+1)*65 + n],      r00, r01);
        half8 bf1 = relu8(stg[p0*65 + 32 + n], stg[(p0+1)*65 + 32 + n], r10, r11);
        half8 w0 = G8(0, 1), w1f = G8(0, 5);
        a00 = MFMA(w0, bf0, a00);  a01 = MFMA(w0, bf1, a01);
        a10 = MFMA(w1f, bf0, a10); a11 = MFMA(w1f, bf1, a11);
    }
    #pragma unroll
    for (int j = 0; j < 8; ++j) stg[qq*65 + j*8 + tg] = c2[j];   // WAR: DS in-order
    #pragma unroll
    for (int ks = 2; ks < 4; ++ks) {
        const int p0 = (ks - 2)*4 + hv*2;
        float4 r00 = *(const float4*)(xr0 + ks*16), r01 = *(const float4*)(xr0 + ks*16 + 4);
        float4 r10 = *(const float4*)(xr1 + ks*16), r11 = *(const float4*)(xr1 + ks*16 + 4);
        half8 bf0 = relu8(stg[p0*65 + n],      stg[(p0+1)*65 + n],      r00, r01);
        half8 bf1 = relu8(stg[p0*65 + 32 + n], stg[(p0+1)*65 + 32 + n], r10, r11);
        half8 w0 = G8(0, ks), w1f = G8(0, 4 + ks);
        a00 = MFMA(w0, bf0, a00);  a01 = MFMA(w0, bf1, a01);
        a10 = MFMA(w1f, bf0, a10); a11 = MFMA(w1f, bf1, a11);
    }
    half8 of[2][4];                          // O frags: feed att1 AND the epilogue
    xform_tile(a00, hv, of[0][0], of[0][1]); xform_tile(a01, hv, of[1][0], of[1][1]);
    xform_tile(a10, hv, of[0][2], of[0][3]); xform_tile(a11, hv, of[1][2], of[1][3]);

    // ======== att1: A1 = relu(Wa1low^T @ O + UB[node] + (ba1 in UB))
    const float* ubrow = UB + (size_t)b * 64;
    {
        const f32x16 bc0 = ldbias(ubrow, hv, 0), bc1 = ldbias(ubrow, hv, 1);
        half8 w0 = G8(4096, 0), w1f = G8(4096, 4);
        a00 = MFMA(w0, of[0][0], bc0);  a01 = MFMA(w0, of[1][0], bc0);
        a10 = MFMA(w1f, of[0][0], bc1); a11 = MFMA(w1f, of[1][0], bc1);
    }
    #pragma unroll
    for (int ks = 1; ks < 4; ++ks) {
        half8 w0 = G8(4096, ks), w1f = G8(4096, 4 + ks);
        a00 = MFMA(w0, of[0][ks], a00);  a01 = MFMA(w0, of[1][ks], a01);
        a10 = MFMA(w1f, of[0][ks], a10); a11 = MFMA(w1f, of[1][ks], a11);
    }
    half8 af[2][4];
    xform_tile(a00, hv, af[0][0], af[0][1]); xform_tile(a01, hv, af[1][0], af[1][1]);
    xform_tile(a10, hv, af[0][2], af[0][3]); xform_tile(a11, hv, af[1][2], af[1][3]);

    // ======== att2 + logits (mt sequential; bias via MFMA C)
    float lg0 = 0.f, lg1 = 0.f;
    #pragma unroll
    for (int mt = 0; mt < 2; ++mt) {
        f32x16 c0, c1v;
        {
            const f32x16 bc = ldbias(tbf + 64, hv, mt);
            half8 wv = G8(8192, mt*4 + 0);
            c0  = MFMA(wv, af[0][0], bc);
            c1v = MFMA(wv, af[1][0], bc);
        }
        #pragma unroll
        for (int ks = 1; ks < 4; ++ks) {
            half8 wv = G8(8192, mt*4 + ks);
            c0  = MFMA(wv, af[0][ks], c0);
            c1v = MFMA(wv, af[1][ks], c1v);
        }
        #pragma unroll
        for (int q = 0; q < 4; ++q) {
            float4 w3 = ((const float4*)(tbf + 128))[hv*8 + mt*4 + q];
            lg0 += fmaxf(c0[4*q], 0.f)*w3.x + fmaxf(c0[4*q+1], 0.f)*w3.y
                 + fmaxf(c0[4*q+2], 0.f)*w3.z + fmaxf(c0[4*q+3], 0.f)*w3.w;
            lg1 += fmaxf(c1v[4*q], 0.f)*w3.x + fmaxf(c1v[4*q+1], 0.f)*w3.y
                 + fmaxf(c1v[4*q+2], 0.f)*w3.z + fmaxf(c1v[4*q+3], 0.f)*w3.w;
        }
    }
    lg0 += __shfl_xor(lg0, 32, 64);
    lg1 += __shfl_xor(lg1, 32, 64);
    if (32 + n >= LH) lg1 = -1e30f;

    // ---- softmax over 64 tokens
    float mx = fmaxf(lg0, lg1);
    #pragma unroll
    for (int off = 16; off >= 1; off >>= 1) mx = fmaxf(mx, __shfl_xor(mx, off, 64));
    const float e0 = __expf(lg0 - mx);
    const float e1 = __expf(lg1 - mx);
    float s = e0 + e1;
    #pragma unroll
    for (int off = 16; off >= 1; off >>= 1) s += __shfl_xor(s, off, 64);
    const float at0 = e0 / s, at1 = e1 / s;

    // ======== epilogue: out[feat] = sum_tok att[tok]*O[feat][tok]
    float cur[32];
    #pragma unroll
    for (int ks = 0; ks < 4; ++ks)
        #pragma unroll
        for (int j = 0; j < 8; ++j)
            cur[ks*8 + j] = at0 * (float)of[0][ks][j] + at1 * (float)of[1][ks][j];
    #pragma unroll
    for (int k = 0; k < 5; ++k) {
        const int d = 1 << k, mybit = (lane >> k) & 1, half = 16 >> k;
        #pragma unroll
        for (int j2 = 0; j2 < 16; ++j2) {
            if (j2 < half) {
                float sel  = mybit ? cur[2*j2]     : cur[2*j2 + 1];
                float got  = __shfl_xor(sel, d, 64);
                float keep = mybit ? cur[2*j2 + 1] : cur[2*j2];
                cur[j2] = keep + got;
            }
        }
    }
    const int feat = ((lane >> 3) & 3)*16 + hv*8 + (lane & 7);
    __builtin_nontemporal_store(cur[0], out + (size_t)b * D + feat);
    #undef G8
}

extern "C" void kernel_launch(void* const* d_in, const int* in_sizes, int n_in,
                              void* d_out, int out_size, void* d_ws, size_t ws_size,
                              hipStream_t stream) {
    const int*   nodes      = (const int*)  d_in[0];
    const int*   history_uv = (const int*)  d_in[1];
    const int*   history_r  = (const int*)  d_in[2];
    const float* v2e        = (const float*)d_in[3];
    const float* u2e        = (const float*)d_in[4];
    const float* r2e        = (const float*)d_in[5];
    const float* w1         = (const float*)d_in[6];
    const float* b1         = (const float*)d_in[7];
    const float* w2         = (const float*)d_in[8];
    const float* b2         = (const float*)d_in[9];
    const float* wa1        = (const float*)d_in[10];
    const float* ba1        = (const float*)d_in[11];
    const float* wa2        = (const float*)d_in[12];
    const float* ba2        = (const float*)d_in[13];
    const float* wa3        = (const float*)d_in[14];
    float* out = (float*)d_out;

    _Float16* wsh = (_Float16*)d_ws;
    float*    tbf = (float*)((char*)d_ws + TBF_OFF);
    float*    UB  = (float*)((char*)d_ws + UB_OFF);
    float*    P1p = (float*)((char*)d_ws + P1_OFF);

    uv_prep<<<80, 256, 0, stream>>>(w1, w2, wa1, wa2, r2e,
                                    b1, b2, ba1, ba2, wa3, wsh, tbf);
    p1_prep<<<782, 256, 0, stream>>>(v2e, wsh, P1p);
    ub_prep<<<128, 256, 0, stream>>>(nodes, u2e, wsh, tbf, UB);
    uv_main<<<NB/4, 256, 0, stream>>>(history_uv, history_r,
                                      P1p, UB, wsh, tbf, out);
}

// Round 4
// 215.230 us; speedup vs baseline: 1.1239x; 1.0254x over previous
//
#include <hip/hip_runtime.h>
#include <math.h>

#define NB 16384
#define LH 50
#define D  64

// workspace layout (bytes):
//   0       : wsh   (f16 weight frags, 3 sections x 4096 halves = 24 KB)
//   49152   : tbf   (f32: b2p[64] ba2p[64] wa3p[64] R1p[5][64] = 512 f)
//   65536   : UB    (f32 [16384][64] permuted, u@A1up + ba1, per node)
//   4259840 : P1p   (f32 [100000][64] permuted, v2e@W1_top, per item)
#define TBF_OFF 49152
#define UB_OFF  65536
#define P1_OFF  4259840

typedef _Float16 half2v __attribute__((ext_vector_type(2)));
typedef _Float16 half8  __attribute__((ext_vector_type(8)));
typedef float    f32x16 __attribute__((ext_vector_type(16)));
typedef unsigned int u32;

#define MFMA(a, b, c) __builtin_amdgcn_mfma_f32_32x32x16_f16((a), (b), (c), 0, 0, 0)

// ---- fragment facts (32x32x16, verified) ----
// A[m][k]: m=lane&31, k=(lane>>5)*8+j (8 contiguous k per lane)
// B[k][n]: n=lane&31, k=(lane>>5)*8+j
// C/D:     col=lane&31, row=(reg&3)+8*(reg>>2)+4*(lane>>5)
// permuted slot t(hv,mt,q) = hv*32+mt*16+q <-> feat = mt*32+(q&3)+8*(q>>2)+4*hv

__device__ __forceinline__ u32 pack2(float a, float b) {
    half2v h; h[0] = (_Float16)a; h[1] = (_Float16)b;
    return __builtin_bit_cast(u32, h);
}
__device__ __forceinline__ half8 mk8(u32 a, u32 b, u32 c, u32 d) {
    uint4 t = make_uint4(a, b, c, d);
    return __builtin_bit_cast(half8, t);
}
__device__ __forceinline__ half8 cvt8(const float* __restrict__ p) {
    float4 u = *(const float4*)p;
    float4 v = *(const float4*)(p + 4);
    return mk8(pack2(u.x, u.y), pack2(u.z, u.w), pack2(v.x, v.y), pack2(v.z, v.w));
}
// relu(stage + rating-row) -> B-frag (layer2 input from f32 pre-acts)
__device__ __forceinline__ half8 relu8(float4 a, float4 b, float4 ra, float4 rb) {
    return mk8(pack2(fmaxf(a.x + ra.x, 0.f), fmaxf(a.y + ra.y, 0.f)),
               pack2(fmaxf(a.z + ra.z, 0.f), fmaxf(a.w + ra.w, 0.f)),
               pack2(fmaxf(b.x + rb.x, 0.f), fmaxf(b.y + rb.y, 0.f)),
               pack2(fmaxf(b.z + rb.z, 0.f), fmaxf(b.w + rb.w, 0.f)));
}

// relu + f16-pack + lane^32 exchange: one C tile -> two B-frags (k-halves)
__device__ __forceinline__ void xform_tile(const f32x16& t, int hv, half8& f0, half8& f1) {
    u32 p[8], rp[8];
    #pragma unroll
    for (int q = 0; q < 8; ++q) p[q] = pack2(fmaxf(t[2*q], 0.f), fmaxf(t[2*q+1], 0.f));
    #pragma unroll
    for (int q = 0; q < 8; ++q) rp[q] = (u32)__shfl_xor((int)p[q], 32, 64);
    f0 = hv ? mk8(rp[2], rp[3], p[2], p[3]) : mk8(p[0], p[1], rp[0], rp[1]);
    f1 = hv ? mk8(rp[6], rp[7], p[6], p[7]) : mk8(p[4], p[5], rp[4], rp[5]);
}

// bias/UB tile from a 64-float permuted row
__device__ __forceinline__ f32x16 ldbias(const float* __restrict__ tb, int hv, int mt) {
    const float4* p = (const float4*)tb + hv*8 + mt*4;
    f32x16 r;
    #pragma unroll
    for (int q = 0; q < 4; ++q) {
        float4 v = p[q];
        r[4*q] = v.x; r[4*q+1] = v.y; r[4*q+2] = v.z; r[4*q+3] = v.w;
    }
    return r;
}

// build an A-frag of a 64x64 row-major f32 weight W on the fly (L1-hot)
__device__ __forceinline__ half8 mkw(const float* __restrict__ W, int ks, int mt,
                                     int hv, int m) {
    half8 r;
    #pragma unroll
    for (int j = 0; j < 8; ++j)
        r[j] = (_Float16)W[(ks*16 + hv*8 + j)*64 + mt*32 + m];
    return r;
}

// ================= K1: ALL prep in one launch (block-range partitioned) ========
// blocks [0,782)   : P1p = v2e @ W1_top        (w1-top frags converted inline)
// blocks [782,910) : UB  = u2e[nodes]@A1up+ba1 (wa1-up frags converted inline)
// blocks [910,958) : wsh sections 0..2 (w2 pi-folded, wa1low, wa2)
// block  958       : tbf tables b2p/ba2p/wa3p
// block  959       : R1p[5][64] (rating rows through layer1, f32 exact)
__global__ __launch_bounds__(256) void prep_all(
    const int*   __restrict__ nodes,
    const float* __restrict__ v2e, const float* __restrict__ u2e,
    const float* __restrict__ r2e,
    const float* __restrict__ w1,  const float* __restrict__ b1,
    const float* __restrict__ w2,  const float* __restrict__ b2,
    const float* __restrict__ wa1, const float* __restrict__ ba1,
    const float* __restrict__ wa2, const float* __restrict__ ba2,
    const float* __restrict__ wa3,
    _Float16* __restrict__ wsh, float* __restrict__ tbf,
    float* __restrict__ UB, float* __restrict__ P1p) {
    const int blk = blockIdx.x;
    const int lane = threadIdx.x & 63;
    const int n = lane & 31, hv = lane >> 5;

    if (blk < 782) {                               // ---- P1p tiles
        const int tile = blk*4 + (threadIdx.x >> 6);
        if (tile >= 3125) return;
        const int item = tile*32 + n;
        half8 bf[4];
        #pragma unroll
        for (int ks = 0; ks < 4; ++ks)
            bf[ks] = cvt8(v2e + (size_t)item*64 + ks*16 + hv*8);
        f32x16 a0, a1;
        #pragma unroll
        for (int q = 0; q < 16; ++q) { a0[q] = 0.f; a1[q] = 0.f; }
        #pragma unroll
        for (int ks = 0; ks < 4; ++ks) {
            a0 = MFMA(mkw(w1, ks, 0, hv, n), bf[ks], a0);
            a1 = MFMA(mkw(w1, ks, 1, hv, n), bf[ks], a1);
        }
        float4* dst = (float4*)(P1p + (size_t)item*64 + hv*32);
        #pragma unroll
        for (int q = 0; q < 4; ++q) {
            dst[q]     = make_float4(a0[4*q], a0[4*q+1], a0[4*q+2], a0[4*q+3]);
            dst[4 + q] = make_float4(a1[4*q], a1[4*q+1], a1[4*q+2], a1[4*q+3]);
        }
        return;
    }
    if (blk < 910) {                               // ---- UB tiles
        const int tile = (blk - 782)*4 + (threadIdx.x >> 6);   // 512 tiles exactly
        const int s = tile*32 + n;
        const int nid = nodes[s];
        half8 bf[4];
        #pragma unroll
        for (int ks = 0; ks < 4; ++ks)
            bf[ks] = cvt8(u2e + (size_t)nid*64 + ks*16 + hv*8);
        f32x16 a0, a1;
        #pragma unroll
        for (int q = 0; q < 16; ++q) {
            a0[q] = ba1[(q & 3) + 8*(q >> 2) + 4*hv];
            a1[q] = ba1[32 + (q & 3) + 8*(q >> 2) + 4*hv];
        }
        const float* wup = wa1 + 64*64;            // wa1 upper half rows
        #pragma unroll
        for (int ks = 0; ks < 4; ++ks) {
            a0 = MFMA(mkw(wup, ks, 0, hv, n), bf[ks], a0);
            a1 = MFMA(mkw(wup, ks, 1, hv, n), bf[ks], a1);
        }
        float4* dst = (float4*)(UB + (size_t)s*64 + hv*32);
        #pragma unroll
        for (int q = 0; q < 4; ++q) {
            dst[q]     = make_float4(a0[4*q], a0[4*q+1], a0[4*q+2], a0[4*q+3]);
            dst[4 + q] = make_float4(a1[4*q], a1[4*q+1], a1[4*q+2], a1[4*q+3]);
        }
        return;
    }
    if (blk < 958) {                               // ---- wsh sections 0..2
        const int idx = (blk - 910)*256 + threadIdx.x;         // [0, 12288)
        const int j = idx & 7, l2 = (idx >> 3) & 63;
        const int hv2 = l2 >> 5, m31 = l2 & 31;
        const int f = (idx >> 9) & 7, ks = f & 3, mt = f >> 2;
        const int sec = idx >> 12;
        const int tau = ks*16 + hv2*8 + j;
        float v;
        if (sec == 0) {       // w2 with k-permutation folded in
            const int thv = (tau >> 5) & 1, tmt = (tau >> 4) & 1, i = tau & 15;
            const int feat = tmt*32 + (i & 3) + 8*(i >> 2) + 4*thv;
            v = w2[feat*64 + mt*32 + m31];
        }
        else if (sec == 1) v = wa1[tau*64 + mt*32 + m31];
        else               v = wa2[tau*64 + mt*32 + m31];
        wsh[idx] = (_Float16)v;
        return;
    }
    if (blk == 958) {                              // ---- tbf tables
        if (threadIdx.x < 64) {
            const int t = threadIdx.x;
            const int thv = t >> 5, r = t & 31, mtt = r >> 4, i = r & 15;
            const int feat = mtt*32 + (i & 3) + 8*(i >> 2) + 4*thv;
            tbf[t]       = b2[feat];
            tbf[64 + t]  = ba2[feat];
            tbf[128 + t] = wa3[feat];
        }
        return;
    }
    {                                              // ---- blk 959: R1p
        #pragma unroll 1
        for (int base = 0; base < 320; base += 256) {
            const int o = base + (int)threadIdx.x;
            if (o < 320) {
                const int rr = o >> 6, tt = o & 63;
                const int thv = tt >> 5, r5 = tt & 31, mtt = r5 >> 4, i = r5 & 15;
                const int feat = mtt*32 + (i & 3) + 8*(i >> 2) + 4*thv;
                float acc = b1[feat];
                for (int k = 0; k < 64; ++k)
                    acc += r2e[rr*64 + k] * w1[(64 + k)*64 + feat];
                tbf[192 + rr*64 + tt] = acc;
            }
        }
    }
}

// ================= K2: fused forward — TWO WAVES per node =================
// Wave owns one 32-token half (nt) x all 64 feats: 24 MFMAs, 2 accumulators
// (32 AGPR vs 64), of/af halved -> ~half the unified-register footprint of R3.
// launch_bounds(256,4) forces <=128 regs/wave = 4 waves/SIMD target.
// Cross-wave: softmax merged via max-rescale (1 barrier), epilogue partial-add
// via LDS (1 barrier). Block = 256 thr = 2 nodes x 2 waves.
__global__ __launch_bounds__(256, 4) void uv_main(
    const int*   __restrict__ huv,
    const int*   __restrict__ hr,
    const float* __restrict__ P1p,
    const float* __restrict__ UB,
    const _Float16* __restrict__ wsh,
    const float* __restrict__ tbf,
    float*       __restrict__ out) {
    __shared__ float4 stage[2][520];         // per-node: 8 planes x 65 units (16B)
    __shared__ float  xch[2][64];            // epilogue partial exchange
    __shared__ float  smx[2][2], ssm[2][2];  // softmax (max, sum) per (node, nt)
    const int tid  = threadIdx.x;
    const int lane = tid & 63;
    const int wid  = tid >> 6;               // 0..3
    const int p    = wid >> 1, nt = wid & 1; // node-in-block, token-half
    const int b    = blockIdx.x * 2 + p;
    const int n = lane & 31, hv = lane >> 5;
    float4* const stg = stage[p];

    #define G8(base, f) (*(const half8*)(wsh + (base) + (size_t)((f)*64 + lane)*8))

    // ---- staging: this wave's 32 rows (tokens nt*32 .. nt*32+31)
    const int tg = lane >> 3;                // row-in-group 0..7
    const int qq = lane & 7;                 // 16B piece within 128B chunk
    int rowid[4];
    #pragma unroll
    for (int j = 0; j < 4; ++j) {
        int t = nt*32 + j*8 + tg; if (t > LH-1) t = LH-1;
        rowid[j] = huv[b*LH + t];
    }
    float4 c1[4];
    #pragma unroll
    for (int j = 0; j < 4; ++j)
        c1[j] = *(const float4*)(P1p + (size_t)rowid[j]*64 + qq*4);

    // rating row (per-token, tiny L1-hot R1p table)
    const int tglob = (nt*32 + n < LH) ? nt*32 + n : LH - 1;
    const int ir = __builtin_nontemporal_load(hr + b*LH + tglob);
    const float* xr = tbf + 192 + ir*64 + hv*8;

    // stage chunk1, then issue chunk2 (c1 regs die at the stage -> reuse)
    #pragma unroll
    for (int j = 0; j < 4; ++j) stg[qq*65 + nt*32 + j*8 + tg] = c1[j];
    float4 c2[4];
    #pragma unroll
    for (int j = 0; j < 4; ++j)
        c2[j] = *(const float4*)(P1p + (size_t)rowid[j]*64 + 32 + qq*4);

    const int tn = nt*32 + n;                // this lane's token column in stage
    // ======== layer 2: O[feat][tok] = W2^T(pi) @ relu(P1+R1) + b2
    f32x16 acc0, acc1;
    {   // ks = 0
        const f32x16 bc0 = ldbias(tbf, hv, 0), bc1 = ldbias(tbf, hv, 1);
        const int p0 = hv*2;
        float4 r0 = *(const float4*)(xr), r1 = *(const float4*)(xr + 4);
        half8 bf = relu8(stg[p0*65 + tn], stg[(p0+1)*65 + tn], r0, r1);
        acc0 = MFMA(G8(0, 0), bf, bc0);
        acc1 = MFMA(G8(0, 4), bf, bc1);
    }
    {   // ks = 1
        const int p0 = 4 + hv*2;
        float4 r0 = *(const float4*)(xr + 16), r1 = *(const float4*)(xr + 20);
        half8 bf = relu8(stg[p0*65 + tn], stg[(p0+1)*65 + tn], r0, r1);
        acc0 = MFMA(G8(0, 1), bf, acc0);
        acc1 = MFMA(G8(0, 5), bf, acc1);
    }
    #pragma unroll
    for (int j = 0; j < 4; ++j) stg[qq*65 + nt*32 + j*8 + tg] = c2[j];  // WAR: DS in-order
    #pragma unroll
    for (int ks = 2; ks < 4; ++ks) {
        const int p0 = (ks - 2)*4 + hv*2;
        float4 r0 = *(const float4*)(xr + ks*16), r1 = *(const float4*)(xr + ks*16 + 4);
        half8 bf = relu8(stg[p0*65 + tn], stg[(p0+1)*65 + tn], r0, r1);
        acc0 = MFMA(G8(0, ks), bf, acc0);
        acc1 = MFMA(G8(0, 4 + ks), bf, acc1);
    }
    half8 of[4];                             // O frags: feed att1 AND the epilogue
    xform_tile(acc0, hv, of[0], of[1]);
    xform_tile(acc1, hv, of[2], of[3]);

    // ======== att1: A1 = relu(Wa1low^T @ O + UB[node])   (ba1 folded in UB)
    const float* ubrow = UB + (size_t)b * 64;
    acc0 = MFMA(G8(4096, 0), of[0], ldbias(ubrow, hv, 0));
    acc1 = MFMA(G8(4096, 4), of[0], ldbias(ubrow, hv, 1));
    #pragma unroll
    for (int ks = 1; ks < 4; ++ks) {
        acc0 = MFMA(G8(4096, ks),     of[ks], acc0);
        acc1 = MFMA(G8(4096, 4 + ks), of[ks], acc1);
    }
    half8 af[4];
    xform_tile(acc0, hv, af[0], af[1]);
    xform_tile(acc1, hv, af[2], af[3]);

    // ======== att2 + logits (mt sequential; bias via MFMA C)
    float lg = 0.f;
    #pragma unroll
    for (int mt = 0; mt < 2; ++mt) {
        f32x16 c = MFMA(G8(8192, mt*4 + 0), af[0], ldbias(tbf + 64, hv, mt));
        #pragma unroll
        for (int ks = 1; ks < 4; ++ks)
            c = MFMA(G8(8192, mt*4 + ks), af[ks], c);
        #pragma unroll
        for (int q = 0; q < 4; ++q) {
            float4 w3 = ((const float4*)(tbf + 128))[hv*8 + mt*4 + q];
            lg += fmaxf(c[4*q], 0.f)*w3.x + fmaxf(c[4*q+1], 0.f)*w3.y
                + fmaxf(c[4*q+2], 0.f)*w3.z + fmaxf(c[4*q+3], 0.f)*w3.w;
        }
    }
    // combine feat-halves across lane^32: lane n holds logit of token nt*32+n
    lg += __shfl_xor(lg, 32, 64);
    if (nt == 1 && 32 + n >= LH) lg = -1e30f;

    // ---- softmax: local (32 tokens) then cross-wave merge via max-rescale
    float mx = lg;
    #pragma unroll
    for (int off = 16; off >= 1; off >>= 1) mx = fmaxf(mx, __shfl_xor(mx, off, 64));
    const float e = __expf(lg - mx);
    float s = e;
    #pragma unroll
    for (int off = 16; off >= 1; off >>= 1) s += __shfl_xor(s, off, 64);
    if (lane == 0) { smx[p][nt] = mx; ssm[p][nt] = s; }
    __syncthreads();
    const float mo = smx[p][nt ^ 1], so = ssm[p][nt ^ 1];
    const float M = fmaxf(mx, mo);
    const float stot = s*__expf(mx - M) + so*__expf(mo - M);
    const float fw = __expf(mx - M) / stot;  // uniform rescale for this wave's e

    // ======== epilogue: partial out over this wave's 32 tokens, then merge
    const float fe = e * fw;                 // this token's attention weight
    float cur[32];
    #pragma unroll
    for (int ks = 0; ks < 4; ++ks)
        #pragma unroll
        for (int j = 0; j < 8; ++j)
            cur[ks*8 + j] = fe * (float)of[ks][j];
    #pragma unroll
    for (int k = 0; k < 5; ++k) {
        const int d = 1 << k, mybit = (lane >> k) & 1, half = 16 >> k;
        #pragma unroll
        for (int j2 = 0; j2 < 16; ++j2) {
            if (j2 < half) {
                float sel  = mybit ? cur[2*j2]     : cur[2*j2 + 1];
                float got  = __shfl_xor(sel, d, 64);
                float keep = mybit ? cur[2*j2 + 1] : cur[2*j2];
                cur[j2] = keep + got;
            }
        }
    }
    const int feat = ((lane >> 3) & 3)*16 + hv*8 + (lane & 7);
    if (nt == 1) xch[p][feat] = cur[0];
    __syncthreads();
    if (nt == 0)
        __builtin_nontemporal_store(cur[0] + xch[p][feat], out + (size_t)b * D + feat);
    #undef G8
}

extern "C" void kernel_launch(void* const* d_in, const int* in_sizes, int n_in,
                              void* d_out, int out_size, void* d_ws, size_t ws_size,
                              hipStream_t stream) {
    const int*   nodes      = (const int*)  d_in[0];
    const int*   history_uv = (const int*)  d_in[1];
    const int*   history_r  = (const int*)  d_in[2];
    const float* v2e        = (const float*)d_in[3];
    const float* u2e        = (const float*)d_in[4];
    const float* r2e        = (const float*)d_in[5];
    const float* w1         = (const float*)d_in[6];
    const float* b1         = (const float*)d_in[7];
    const float* w2         = (const float*)d_in[8];
    const float* b2         = (const float*)d_in[9];
    const float* wa1        = (const float*)d_in[10];
    const float* ba1        = (const float*)d_in[11];
    const float* wa2        = (const float*)d_in[12];
    const float* ba2        = (const float*)d_in[13];
    const float* wa3        = (const float*)d_in[14];
    float* out = (float*)d_out;

    _Float16* wsh = (_Float16*)d_ws;
    float*    tbf = (float*)((char*)d_ws + TBF_OFF);
    float*    UB  = (float*)((char*)d_ws + UB_OFF);
    float*    P1p = (float*)((char*)d_ws + P1_OFF);

    prep_all<<<960, 256, 0, stream>>>(nodes, v2e, u2e, r2e, w1, b1, w2, b2,
                                      wa1, ba1, wa2, ba2, wa3, wsh, tbf, UB, P1p);
    uv_main<<<NB/2, 256, 0, stream>>>(history_uv, history_r,
                                      P1p, UB, wsh, tbf, out);
}

// Round 5
// 197.435 us; speedup vs baseline: 1.2252x; 1.0901x over previous
//
#include <hip/hip_runtime.h>
#include <math.h>

#define NB 16384
#define LH 50
#define D  64

// workspace layout (bytes):
//   0       : wsh  (f16 weight frags, 3 sections x 4096 halves = 24 KB)
//   49152   : tbf  (f32: b2p[64] ba2p[64] wa3p[64] | R1h f16[5][64] @ f32-idx 192)
//   65536   : UB   (f32 [16384][64] permuted, u@A1up + ba1, per node)
//   4259840 : P1h  (f16 [100000][64] permuted slot order, v2e@W1_top)
#define TBF_OFF 49152
#define UB_OFF  65536
#define P1_OFF  4259840

typedef _Float16 half2v __attribute__((ext_vector_type(2)));
typedef _Float16 half8  __attribute__((ext_vector_type(8)));
typedef float    f32x16 __attribute__((ext_vector_type(16)));
typedef unsigned int u32;

#define MFMA(a, b, c) __builtin_amdgcn_mfma_f32_32x32x16_f16((a), (b), (c), 0, 0, 0)

// ---- fragment facts (32x32x16, verified) ----
// A[m][k]: m=lane&31, k=(lane>>5)*8+j (8 contiguous k per lane)
// B[k][n]: n=lane&31, k=(lane>>5)*8+j
// C/D:     col=lane&31, row=(reg&3)+8*(reg>>2)+4*(lane>>5)
// permuted slot t(hv,mt,q) = hv*32+mt*16+q <-> feat = mt*32+(q&3)+8*(q>>2)+4*hv

__device__ __forceinline__ u32 pack2(float a, float b) {
    half2v h; h[0] = (_Float16)a; h[1] = (_Float16)b;
    return __builtin_bit_cast(u32, h);
}
__device__ __forceinline__ half8 mk8(u32 a, u32 b, u32 c, u32 d) {
    uint4 t = make_uint4(a, b, c, d);
    return __builtin_bit_cast(half8, t);
}
__device__ __forceinline__ half8 cvt8(const float* __restrict__ p) {
    float4 u = *(const float4*)p;
    float4 v = *(const float4*)(p + 4);
    return mk8(pack2(u.x, u.y), pack2(u.z, u.w), pack2(v.x, v.y), pack2(v.z, v.w));
}
// f16 add + relu (compiles to v_pk_add_f16 / v_pk_max_f16)
__device__ __forceinline__ half8 addrelu8(half8 a, half8 r) {
    half8 s = a + r;
    #pragma unroll
    for (int j = 0; j < 8; ++j) s[j] = s[j] > (_Float16)0 ? s[j] : (_Float16)0;
    return s;
}

// relu + f16-pack + lane^32 exchange: one C tile -> two B-frags (k-halves)
__device__ __forceinline__ void xform_tile(const f32x16& t, int hv, half8& f0, half8& f1) {
    u32 p[8], rp[8];
    #pragma unroll
    for (int q = 0; q < 8; ++q) p[q] = pack2(fmaxf(t[2*q], 0.f), fmaxf(t[2*q+1], 0.f));
    #pragma unroll
    for (int q = 0; q < 8; ++q) rp[q] = (u32)__shfl_xor((int)p[q], 32, 64);
    f0 = hv ? mk8(rp[2], rp[3], p[2], p[3]) : mk8(p[0], p[1], rp[0], rp[1]);
    f1 = hv ? mk8(rp[6], rp[7], p[6], p[7]) : mk8(p[4], p[5], rp[4], rp[5]);
}

// bias/UB tile from a 64-float permuted row
__device__ __forceinline__ f32x16 ldbias(const float* __restrict__ tb, int hv, int mt) {
    const float4* p = (const float4*)tb + hv*8 + mt*4;
    f32x16 r;
    #pragma unroll
    for (int q = 0; q < 4; ++q) {
        float4 v = p[q];
        r[4*q] = v.x; r[4*q+1] = v.y; r[4*q+2] = v.z; r[4*q+3] = v.w;
    }
    return r;
}

// build an A-frag of a 64x64 row-major f32 weight W on the fly (L1/L2-hot)
__device__ __forceinline__ half8 mkw(const float* __restrict__ W, int ks, int mt,
                                     int hv, int m) {
    half8 r;
    #pragma unroll
    for (int j = 0; j < 8; ++j)
        r[j] = (_Float16)W[(ks*16 + hv*8 + j)*64 + mt*32 + m];
    return r;
}

// ================= K1: ALL prep in one launch (block-range partitioned) ========
// blocks [0,782)   : P1h = f16(v2e @ W1_top)   (w1-top frags converted inline)
// blocks [782,910) : UB  = u2e[nodes]@A1up+ba1 (wa1-up frags converted inline)
// blocks [910,958) : wsh sections 0..2 (w2 pi-folded, wa1low, wa2)
// block  958       : tbf tables b2p/ba2p/wa3p
// block  959       : R1h[5][64] f16 (rating rows through layer1, f32 math)
__global__ __launch_bounds__(256) void prep_all(
    const int*   __restrict__ nodes,
    const float* __restrict__ v2e, const float* __restrict__ u2e,
    const float* __restrict__ r2e,
    const float* __restrict__ w1,  const float* __restrict__ b1,
    const float* __restrict__ w2,  const float* __restrict__ b2,
    const float* __restrict__ wa1, const float* __restrict__ ba1,
    const float* __restrict__ wa2, const float* __restrict__ ba2,
    const float* __restrict__ wa3,
    _Float16* __restrict__ wsh, float* __restrict__ tbf,
    float* __restrict__ UB, _Float16* __restrict__ P1h) {
    const int blk = blockIdx.x;
    const int lane = threadIdx.x & 63;
    const int n = lane & 31, hv = lane >> 5;

    if (blk < 782) {                               // ---- P1h tiles (f16 rows)
        const int tile = blk*4 + (threadIdx.x >> 6);
        if (tile >= 3125) return;
        const int item = tile*32 + n;
        half8 bf[4];
        #pragma unroll
        for (int ks = 0; ks < 4; ++ks)
            bf[ks] = cvt8(v2e + (size_t)item*64 + ks*16 + hv*8);
        f32x16 a0, a1;
        #pragma unroll
        for (int q = 0; q < 16; ++q) { a0[q] = 0.f; a1[q] = 0.f; }
        #pragma unroll
        for (int ks = 0; ks < 4; ++ks) {
            a0 = MFMA(mkw(w1, ks, 0, hv, n), bf[ks], a0);
            a1 = MFMA(mkw(w1, ks, 1, hv, n), bf[ks], a1);
        }
        u32 dw[16];
        #pragma unroll
        for (int q = 0; q < 8; ++q) dw[q]     = pack2(a0[2*q], a0[2*q+1]);
        #pragma unroll
        for (int q = 0; q < 8; ++q) dw[8 + q] = pack2(a1[2*q], a1[2*q+1]);
        uint4* dst = (uint4*)(P1h + (size_t)item*64 + hv*32);
        dst[0] = make_uint4(dw[0],  dw[1],  dw[2],  dw[3]);
        dst[1] = make_uint4(dw[4],  dw[5],  dw[6],  dw[7]);
        dst[2] = make_uint4(dw[8],  dw[9],  dw[10], dw[11]);
        dst[3] = make_uint4(dw[12], dw[13], dw[14], dw[15]);
        return;
    }
    if (blk < 910) {                               // ---- UB tiles
        const int tile = (blk - 782)*4 + (threadIdx.x >> 6);   // 512 tiles exactly
        const int s = tile*32 + n;
        const int nid = nodes[s];
        half8 bf[4];
        #pragma unroll
        for (int ks = 0; ks < 4; ++ks)
            bf[ks] = cvt8(u2e + (size_t)nid*64 + ks*16 + hv*8);
        f32x16 a0, a1;
        #pragma unroll
        for (int q = 0; q < 16; ++q) {
            a0[q] = ba1[(q & 3) + 8*(q >> 2) + 4*hv];
            a1[q] = ba1[32 + (q & 3) + 8*(q >> 2) + 4*hv];
        }
        const float* wup = wa1 + 64*64;            // wa1 upper half rows
        #pragma unroll
        for (int ks = 0; ks < 4; ++ks) {
            a0 = MFMA(mkw(wup, ks, 0, hv, n), bf[ks], a0);
            a1 = MFMA(mkw(wup, ks, 1, hv, n), bf[ks], a1);
        }
        float4* dst = (float4*)(UB + (size_t)s*64 + hv*32);
        #pragma unroll
        for (int q = 0; q < 4; ++q) {
            dst[q]     = make_float4(a0[4*q], a0[4*q+1], a0[4*q+2], a0[4*q+3]);
            dst[4 + q] = make_float4(a1[4*q], a1[4*q+1], a1[4*q+2], a1[4*q+3]);
        }
        return;
    }
    if (blk < 958) {                               // ---- wsh sections 0..2
        const int idx = (blk - 910)*256 + threadIdx.x;         // [0, 12288)
        const int j = idx & 7, l2 = (idx >> 3) & 63;
        const int hv2 = l2 >> 5, m31 = l2 & 31;
        const int f = (idx >> 9) & 7, ks = f & 3, mt = f >> 2;
        const int sec = idx >> 12;
        const int tau = ks*16 + hv2*8 + j;
        float v;
        if (sec == 0) {       // w2 with k-permutation folded in
            const int thv = (tau >> 5) & 1, tmt = (tau >> 4) & 1, i = tau & 15;
            const int feat = tmt*32 + (i & 3) + 8*(i >> 2) + 4*thv;
            v = w2[feat*64 + mt*32 + m31];
        }
        else if (sec == 1) v = wa1[tau*64 + mt*32 + m31];
        else               v = wa2[tau*64 + mt*32 + m31];
        wsh[idx] = (_Float16)v;
        return;
    }
    if (blk == 958) {                              // ---- tbf tables
        if (threadIdx.x < 64) {
            const int t = threadIdx.x;
            const int thv = t >> 5, r = t & 31, mtt = r >> 4, i = r & 15;
            const int feat = mtt*32 + (i & 3) + 8*(i >> 2) + 4*thv;
            tbf[t]       = b2[feat];
            tbf[64 + t]  = ba2[feat];
            tbf[128 + t] = wa3[feat];
        }
        return;
    }
    {                                              // ---- blk 959: R1h (f16)
        _Float16* R1h = (_Float16*)(tbf + 192);
        #pragma unroll 1
        for (int base = 0; base < 320; base += 256) {
            const int o = base + (int)threadIdx.x;
            if (o < 320) {
                const int rr = o >> 6, tt = o & 63;
                const int thv = tt >> 5, r5 = tt & 31, mtt = r5 >> 4, i = r5 & 15;
                const int feat = mtt*32 + (i & 3) + 8*(i >> 2) + 4*thv;
                float acc = b1[feat];
                for (int k = 0; k < 64; ++k)
                    acc += r2e[rr*64 + k] * w1[(64 + k)*64 + feat];
                R1h[rr*64 + tt] = (_Float16)acc;
            }
        }
    }
}

// ================= K2: fused forward — 1 NODE/WAVE, register-dieted ============
// 4 independent waves/block (no barriers). f16 P1h gather = single 8x16B chunk;
// bf built via pk_add/pk_max f16. mt-sequential layer2/att1/att2 keeps live
// accumulators at 32 AGPR. launch_bounds(256,4) -> <=128 unified regs ->
// 4 waves/SIMD, each a FULL node: ~2.5x nodes-in-flight vs R3.
__global__ __launch_bounds__(256, 4) void uv_main(
    const int*   __restrict__ huv,
    const int*   __restrict__ hr,
    const _Float16* __restrict__ P1h,
    const float* __restrict__ UB,
    const _Float16* __restrict__ wsh,
    const float* __restrict__ tbf,
    float*       __restrict__ out) {
    __shared__ float4 stage[4][520];         // per-wave: 8 planes x 65 units (16B)
    const int lane = threadIdx.x & 63;
    const int w = threadIdx.x >> 6;
    const int b = blockIdx.x * 4 + w;        // node id
    const int n = lane & 31, hv = lane >> 5;
    float4* const stg = stage[w];

    #define G8(base, f) (*(const half8*)(wsh + (base) + (size_t)((f)*64 + lane)*8))

    // ---- gather: lane loads 16B piece qq of rows t = j*8+tg (f16 rows = 128B)
    const int tg = lane >> 3;
    const int qq = lane & 7;
    int rowid[8];
    #pragma unroll
    for (int j = 0; j < 8; ++j) {
        int t = j*8 + tg; if (t > LH-1) t = LH-1;
        rowid[j] = huv[b*LH + t];
    }
    float4 c[8];
    #pragma unroll
    for (int j = 0; j < 8; ++j)
        c[j] = *(const float4*)(P1h + (size_t)rowid[j]*64 + qq*8);

    // rating rows (f16 table, 640B, L1-hot)
    const _Float16* R1h = (const _Float16*)(tbf + 192);
    const int t1  = (32 + n < LH) ? 32 + n : LH - 1;
    const int ir0 = __builtin_nontemporal_load(hr + b*LH + n);
    const int ir1 = __builtin_nontemporal_load(hr + b*LH + t1);

    #pragma unroll
    for (int j = 0; j < 8; ++j) stg[qq*65 + j*8 + tg] = c[j];

    // ---- bf[nt][ks] = relu_f16(P1h + R1h): 1 ds_read_b128 + pk ops each
    half8 bf[2][4];
    #pragma unroll
    for (int ks = 0; ks < 4; ++ks) {
        half8 r0 = *(const half8*)(R1h + ir0*64 + ks*16 + hv*8);
        half8 r1 = *(const half8*)(R1h + ir1*64 + ks*16 + hv*8);
        bf[0][ks] = addrelu8(*(const half8*)&stg[(2*ks + hv)*65 + n],      r0);
        bf[1][ks] = addrelu8(*(const half8*)&stg[(2*ks + hv)*65 + 32 + n], r1);
    }

    // ======== layer 2 (mt-sequential): O = W2^T(pi) @ H + b2
    half8 of[2][4];                          // O frags: feed att1 AND the epilogue
    #pragma unroll
    for (int mt = 0; mt < 2; ++mt) {
        f32x16 a0 = ldbias(tbf, hv, mt);
        f32x16 a1 = ldbias(tbf, hv, mt);
        #pragma unroll
        for (int ks = 0; ks < 4; ++ks) {
            half8 wv = G8(0, mt*4 + ks);
            a0 = MFMA(wv, bf[0][ks], a0);
            a1 = MFMA(wv, bf[1][ks], a1);
        }
        xform_tile(a0, hv, of[0][mt*2], of[0][mt*2 + 1]);
        xform_tile(a1, hv, of[1][mt*2], of[1][mt*2 + 1]);
    }

    // ======== att1 (mt-sequential): A1 = relu(Wa1low^T @ O + UB[node])
    const float* ubrow = UB + (size_t)b * 64;
    half8 af[2][4];
    #pragma unroll
    for (int mt = 0; mt < 2; ++mt) {
        f32x16 a0 = ldbias(ubrow, hv, mt);
        f32x16 a1 = ldbias(ubrow, hv, mt);
        #pragma unroll
        for (int ks = 0; ks < 4; ++ks) {
            half8 wv = G8(4096, mt*4 + ks);
            a0 = MFMA(wv, of[0][ks], a0);
            a1 = MFMA(wv, of[1][ks], a1);
        }
        xform_tile(a0, hv, af[0][mt*2], af[0][mt*2 + 1]);
        xform_tile(a1, hv, af[1][mt*2], af[1][mt*2 + 1]);
    }

    // ======== att2 + logits (mt-sequential; bias via MFMA C)
    float lg0 = 0.f, lg1 = 0.f;
    #pragma unroll
    for (int mt = 0; mt < 2; ++mt) {
        f32x16 c0, c1v;
        {
            const f32x16 bc = ldbias(tbf + 64, hv, mt);
            half8 wv = G8(8192, mt*4 + 0);
            c0  = MFMA(wv, af[0][0], bc);
            c1v = MFMA(wv, af[1][0], bc);
        }
        #pragma unroll
        for (int ks = 1; ks < 4; ++ks) {
            half8 wv = G8(8192, mt*4 + ks);
            c0  = MFMA(wv, af[0][ks], c0);
            c1v = MFMA(wv, af[1][ks], c1v);
        }
        #pragma unroll
        for (int q = 0; q < 4; ++q) {
            float4 w3 = ((const float4*)(tbf + 128))[hv*8 + mt*4 + q];
            lg0 += fmaxf(c0[4*q], 0.f)*w3.x + fmaxf(c0[4*q+1], 0.f)*w3.y
                 + fmaxf(c0[4*q+2], 0.f)*w3.z + fmaxf(c0[4*q+3], 0.f)*w3.w;
            lg1 += fmaxf(c1v[4*q], 0.f)*w3.x + fmaxf(c1v[4*q+1], 0.f)*w3.y
                 + fmaxf(c1v[4*q+2], 0.f)*w3.z + fmaxf(c1v[4*q+3], 0.f)*w3.w;
        }
    }
    // combine feat-halves across lane^32: lane holds logits of tokens n, n+32
    lg0 += __shfl_xor(lg0, 32, 64);
    lg1 += __shfl_xor(lg1, 32, 64);
    if (32 + n >= LH) lg1 = -1e30f;

    // ---- softmax over 64 tokens (butterfly over the 32 token-lanes)
    float mx = fmaxf(lg0, lg1);
    #pragma unroll
    for (int off = 16; off >= 1; off >>= 1) mx = fmaxf(mx, __shfl_xor(mx, off, 64));
    const float e0 = __expf(lg0 - mx);
    const float e1 = __expf(lg1 - mx);       // masked token: exp(-huge)=0
    float s = e0 + e1;
    #pragma unroll
    for (int off = 16; off >= 1; off >>= 1) s += __shfl_xor(s, off, 64);
    const float at0 = e0 / s, at1 = e1 / s;

    // ======== epilogue: out[feat] = sum_tok att[tok]*O[feat][tok]
    float cur[32];
    #pragma unroll
    for (int ks = 0; ks < 4; ++ks)
        #pragma unroll
        for (int j = 0; j < 8; ++j)
            cur[ks*8 + j] = at0 * (float)of[0][ks][j] + at1 * (float)of[1][ks][j];
    #pragma unroll
    for (int k = 0; k < 5; ++k) {
        const int d = 1 << k, mybit = (lane >> k) & 1, half = 16 >> k;
        #pragma unroll
        for (int j2 = 0; j2 < 16; ++j2) {
            if (j2 < half) {
                float sel  = mybit ? cur[2*j2]     : cur[2*j2 + 1];
                float got  = __shfl_xor(sel, d, 64);
                float keep = mybit ? cur[2*j2 + 1] : cur[2*j2];
                cur[j2] = keep + got;
            }
        }
    }
    const int feat = ((lane >> 3) & 3)*16 + hv*8 + (lane & 7);
    __builtin_nontemporal_store(cur[0], out + (size_t)b * D + feat);
    #undef G8
}

extern "C" void kernel_launch(void* const* d_in, const int* in_sizes, int n_in,
                              void* d_out, int out_size, void* d_ws, size_t ws_size,
                              hipStream_t stream) {
    const int*   nodes      = (const int*)  d_in[0];
    const int*   history_uv = (const int*)  d_in[1];
    const int*   history_r  = (const int*)  d_in[2];
    const float* v2e        = (const float*)d_in[3];
    const float* u2e        = (const float*)d_in[4];
    const float* r2e        = (const float*)d_in[5];
    const float* w1         = (const float*)d_in[6];
    const float* b1         = (const float*)d_in[7];
    const float* w2         = (const float*)d_in[8];
    const float* b2         = (const float*)d_in[9];
    const float* wa1        = (const float*)d_in[10];
    const float* ba1        = (const float*)d_in[11];
    const float* wa2        = (const float*)d_in[12];
    const float* ba2        = (const float*)d_in[13];
    const float* wa3        = (const float*)d_in[14];
    float* out = (float*)d_out;

    _Float16* wsh = (_Float16*)d_ws;
    float*    tbf = (float*)((char*)d_ws + TBF_OFF);
    float*    UB  = (float*)((char*)d_ws + UB_OFF);
    _Float16* P1h = (_Float16*)((char*)d_ws + P1_OFF);

    prep_all<<<960, 256, 0, stream>>>(nodes, v2e, u2e, r2e, w1, b1, w2, b2,
                                      wa1, ba1, wa2, ba2, wa3, wsh, tbf, UB, P1h);
    uv_main<<<NB/4, 256, 0, stream>>>(history_uv, history_r,
                                      P1h, UB, wsh, tbf, out);
}